// Round 1
// baseline (5689.762 us; speedup 1.0000x reference)
//
#include <hip/hip_runtime.h>
#include <math.h>

#define N_NODES 50000
#define N_EDGES 400000
#define EN_TOT  450000
#define IN_DIM  128
#define H_HEADS 8
#define C_CH    32
#define HC      256
#define NEG_SLOPE 0.2f

// ---------------- workspace layout (in floats) ----------------
#define OFF_XL    0                                   // x_l  [N, 256]
#define OFF_XR    (OFF_XL + N_NODES * HC)             // x_r  [N, 256]
#define OFF_PROJ  (OFF_XR + N_NODES * HC)             // proj [N, 32]
#define OFF_AEXP  (OFF_PROJ + N_NODES * C_CH)         // aexp [E+N, 8]
#define OFF_DENOM (OFF_AEXP + EN_TOT * H_HEADS)       // denom[N, 8]
#define OFF_ORAW  (OFF_DENOM + N_NODES * H_HEADS)     // oraw [N, 256]  (contiguous w/ denom for one memset)
#define OFF_PART  (OFF_ORAW + N_NODES * HC)           // partial sums [1024]
#define OFF_MEAN  (OFF_PART + 1024)                   // mean scalar [1]
#define WS_FLOATS (OFF_MEAN + 1)

// ---------------- edge_attr mean (deterministic 2-stage) ----------------
__global__ void mean_part_kernel(const float* __restrict__ ea, float* __restrict__ part) {
    __shared__ float sd[256];
    int t = threadIdx.x;
    float s = 0.f;
    for (int i = blockIdx.x * 256 + t; i < N_EDGES; i += 1024 * 256) s += ea[i];
    sd[t] = s; __syncthreads();
    for (int w = 128; w > 0; w >>= 1) { if (t < w) sd[t] += sd[t + w]; __syncthreads(); }
    if (t == 0) part[blockIdx.x] = sd[0];
}

__global__ void mean_final_kernel(const float* __restrict__ part, float* __restrict__ mean_out) {
    __shared__ float sd[256];
    int t = threadIdx.x;
    float s = part[t] + part[t + 256] + part[t + 512] + part[t + 768];
    sd[t] = s; __syncthreads();
    for (int w = 128; w > 0; w >>= 1) { if (t < w) sd[t] += sd[t + w]; __syncthreads(); }
    if (t == 0) mean_out[0] = sd[0] / (float)N_EDGES;
}

// ---------------- fused GEMM: [x_l | x_r | proj] = x @ [W_l|W_r|W_proj]^T ----------------
// M=50000, Nout=544 (256+256+32), K=128.  64x64 tile, 256 threads, 4x4 micro-tile.
#define BM 64
#define BN 64
#define LDSS 132   // padded stride (floats): keeps float4 alignment, breaks bank conflicts

__global__ __launch_bounds__(256) void gemm_xw_kernel(
    const float* __restrict__ x,
    const float* __restrict__ Wl, const float* __restrict__ Wr, const float* __restrict__ Wproj,
    float* __restrict__ xl, float* __restrict__ xr, float* __restrict__ proj)
{
    __shared__ float As[BM * LDSS];
    __shared__ float Bs[BN * LDSS];
    const int m0 = blockIdx.x * BM;
    const int n0 = blockIdx.y * BN;
    const int t = threadIdx.x;

    // stage A tile (64 rows x 128 k) as float4
    for (int ch = t; ch < BM * 32; ch += 256) {
        int r = ch >> 5, c4 = ch & 31;
        int row = m0 + r;
        float4 v = make_float4(0.f, 0.f, 0.f, 0.f);
        if (row < N_NODES) v = ((const float4*)(x + (size_t)row * IN_DIM))[c4];
        *((float4*)(As + r * LDSS + c4 * 4)) = v;
    }
    // stage B tile (combined weight rows n0..n0+63)
    for (int ch = t; ch < BN * 32; ch += 256) {
        int r = ch >> 5, c4 = ch & 31;
        int j = n0 + r;
        float4 v = make_float4(0.f, 0.f, 0.f, 0.f);
        if (j < 256)      v = ((const float4*)(Wl + (size_t)j * IN_DIM))[c4];
        else if (j < 512) v = ((const float4*)(Wr + (size_t)(j - 256) * IN_DIM))[c4];
        else if (j < 544) v = ((const float4*)(Wproj + (size_t)(j - 512) * IN_DIM))[c4];
        *((float4*)(Bs + r * LDSS + c4 * 4)) = v;
    }
    __syncthreads();

    const int tr = t >> 4;   // 0..15 -> rows 4*tr+i
    const int tc = t & 15;   // 0..15 -> cols tc+16*j
    float acc[4][4] = {};
    #pragma unroll
    for (int k4 = 0; k4 < 32; ++k4) {
        float4 a[4], b[4];
        #pragma unroll
        for (int i = 0; i < 4; ++i) a[i] = *((const float4*)(As + (4 * tr + i) * LDSS + k4 * 4));
        #pragma unroll
        for (int j = 0; j < 4; ++j) b[j] = *((const float4*)(Bs + (tc + 16 * j) * LDSS + k4 * 4));
        #pragma unroll
        for (int i = 0; i < 4; ++i)
            #pragma unroll
            for (int j = 0; j < 4; ++j)
                acc[i][j] += a[i].x * b[j].x + a[i].y * b[j].y + a[i].z * b[j].z + a[i].w * b[j].w;
    }

    #pragma unroll
    for (int i = 0; i < 4; ++i) {
        int row = m0 + 4 * tr + i;
        if (row >= N_NODES) continue;
        #pragma unroll
        for (int j = 0; j < 4; ++j) {
            int col = n0 + tc + 16 * j;
            float v = acc[i][j];
            if (col < 256)      xl[(size_t)row * HC + col] = v;
            else if (col < 512) xr[(size_t)row * HC + (col - 256)] = v;
            else if (col < 544) proj[(size_t)row * C_CH + (col - 512)] = v;
        }
    }
}

// ---------------- edge pass: logits + exp + fused atomic aggregation ----------------
// one wave (64 lanes) per edge; 4 edges per 256-thread block
__global__ __launch_bounds__(256) void edge_kernel(
    const int* __restrict__ ei, const float* __restrict__ edge_attr,
    const float* __restrict__ We, const float* __restrict__ att,
    const float* __restrict__ xl, const float* __restrict__ xr,
    const float* __restrict__ mean_attr,
    float* __restrict__ aexp_out, float* __restrict__ denom, float* __restrict__ oraw)
{
    const int lane = threadIdx.x & 63;
    const int e = blockIdx.x * 4 + (threadIdx.x >> 6);
    if (e >= EN_TOT) return;

    int s, d; float eav;
    if (e < N_EDGES) { s = ei[e]; d = ei[N_EDGES + e]; eav = edge_attr[e]; }
    else { s = e - N_EDGES; d = s; eav = mean_attr[0]; }

    const float4 we = ((const float4*)We)[lane];     // W_e[4l..4l+3]
    const float4 at = ((const float4*)att)[lane];    // att flat [8*32]
    const float4 vl = ((const float4*)(xl + (size_t)s * HC))[lane];
    const float4 vr = ((const float4*)(xr + (size_t)d * HC))[lane];

    float m0 = vl.x + vr.x + eav * we.x;
    float m1 = vl.y + vr.y + eav * we.y;
    float m2 = vl.z + vr.z + eav * we.z;
    float m3 = vl.w + vr.w + eav * we.w;
    m0 = (m0 > 0.f) ? m0 : NEG_SLOPE * m0;
    m1 = (m1 > 0.f) ? m1 : NEG_SLOPE * m1;
    m2 = (m2 > 0.f) ? m2 : NEG_SLOPE * m2;
    m3 = (m3 > 0.f) ? m3 : NEG_SLOPE * m3;
    float ssum = m0 * at.x + m1 * at.y + m2 * at.z + m3 * at.w;

    // reduce over the 8 lanes of this head (lanes 8h..8h+7)
    ssum += __shfl_xor(ssum, 1);
    ssum += __shfl_xor(ssum, 2);
    ssum += __shfl_xor(ssum, 4);

    const float aex = expf(ssum);   // no max-subtraction: logits are O(1), exp-safe in fp32
    const int h = lane >> 3;
    if ((lane & 7) == 0) {
        aexp_out[(size_t)e * H_HEADS + h] = aex;
        unsafeAtomicAdd(&denom[(size_t)d * H_HEADS + h], aex);
    }

    float* dstp = oraw + (size_t)d * HC + lane * 4;
    unsafeAtomicAdd(dstp + 0, aex * vl.x);
    unsafeAtomicAdd(dstp + 1, aex * vl.y);
    unsafeAtomicAdd(dstp + 2, aex * vl.z);
    unsafeAtomicAdd(dstp + 3, aex * vl.w);
}

// ---------------- node finalize: mean over heads, relu, +bias, +proj ----------------
__global__ __launch_bounds__(256) void finalize_kernel(
    const float* __restrict__ oraw, const float* __restrict__ denom,
    const float* __restrict__ proj, const float* __restrict__ bias,
    float* __restrict__ xnew)
{
    int idx = blockIdx.x * 256 + threadIdx.x;   // n*32 + c
    if (idx >= N_NODES * C_CH) return;
    int n = idx >> 5, c = idx & 31;
    float acc = 0.f;
    #pragma unroll
    for (int h = 0; h < H_HEADS; ++h)
        acc += oraw[(size_t)n * HC + h * C_CH + c] / denom[(size_t)n * H_HEADS + h];
    acc = acc * (1.f / H_HEADS) + bias[c];
    xnew[idx] = fmaxf(acc, 0.f) + proj[idx];
}

// ---------------- normalized alpha write ----------------
__global__ __launch_bounds__(256) void alpha_kernel(
    const int* __restrict__ ei, const float* __restrict__ aexp,
    const float* __restrict__ denom, float* __restrict__ alpha_out)
{
    int idx = blockIdx.x * 256 + threadIdx.x;   // e*8 + h
    if (idx >= EN_TOT * H_HEADS) return;
    int e = idx >> 3, h = idx & 7;
    int d = (e < N_EDGES) ? ei[N_EDGES + e] : (e - N_EDGES);
    alpha_out[idx] = aexp[idx] / denom[(size_t)d * H_HEADS + h];
}

extern "C" void kernel_launch(void* const* d_in, const int* in_sizes, int n_in,
                              void* d_out, int out_size, void* d_ws, size_t ws_size,
                              hipStream_t stream) {
    const float* x         = (const float*)d_in[0];
    const int*   ei        = (const int*)d_in[1];
    const float* edge_attr = (const float*)d_in[2];
    // d_in[3] = batch (unused)
    const float* Wl        = (const float*)d_in[4];
    const float* Wr        = (const float*)d_in[5];
    const float* We        = (const float*)d_in[6];
    const float* att       = (const float*)d_in[7];
    const float* bias      = (const float*)d_in[8];
    const float* Wproj     = (const float*)d_in[9];

    float* ws    = (float*)d_ws;
    float* xl    = ws + OFF_XL;
    float* xr    = ws + OFF_XR;
    float* proj  = ws + OFF_PROJ;
    float* aexp  = ws + OFF_AEXP;
    float* denom = ws + OFF_DENOM;
    float* oraw  = ws + OFF_ORAW;
    float* part  = ws + OFF_PART;
    float* meanp = ws + OFF_MEAN;

    float* out_xnew  = (float*)d_out;
    float* out_alpha = (float*)d_out + (size_t)N_NODES * C_CH;

    // zero denom + oraw (contiguous)
    hipMemsetAsync(denom, 0, (size_t)(N_NODES * H_HEADS + N_NODES * HC) * sizeof(float), stream);

    mean_part_kernel<<<1024, 256, 0, stream>>>(edge_attr, part);
    mean_final_kernel<<<1, 256, 0, stream>>>(part, meanp);

    dim3 ggrid((N_NODES + BM - 1) / BM, (544 + BN - 1) / BN);
    gemm_xw_kernel<<<ggrid, 256, 0, stream>>>(x, Wl, Wr, Wproj, xl, xr, proj);

    edge_kernel<<<EN_TOT / 4, 256, 0, stream>>>(ei, edge_attr, We, att, xl, xr, meanp,
                                                aexp, denom, oraw);

    finalize_kernel<<<(N_NODES * C_CH) / 256, 256, 0, stream>>>(oraw, denom, proj, bias, out_xnew);

    alpha_kernel<<<(EN_TOT * H_HEADS + 255) / 256, 256, 0, stream>>>(ei, aexp, denom, out_alpha);
}

// Round 2
// 1684.640 us; speedup vs baseline: 3.3774x; 3.3774x over previous
//
#include <hip/hip_runtime.h>
#include <math.h>

#define N_NODES 50000
#define N_EDGES 400000
#define EN_TOT  450000
#define IN_DIM  128
#define H_HEADS 8
#define C_CH    32
#define HC      256
#define NEG_SLOPE 0.2f

// ---------------- workspace layout (in floats) ----------------
#define OFF_XL    0                                   // x_l  [N, 256]
#define OFF_XR    (OFF_XL + N_NODES * HC)             // x_r  [N, 256]
#define OFF_PROJ  (OFF_XR + N_NODES * HC)             // proj [N, 32]
#define OFF_AEXP  (OFF_PROJ + N_NODES * C_CH)         // aexp [E+N, 8]
#define OFF_DENOM (OFF_AEXP + EN_TOT * H_HEADS)       // denom[N, 8]
#define OFF_ORAW  (OFF_DENOM + N_NODES * H_HEADS)     // oraw [N, 256]  (contiguous w/ denom for one memset)
#define OFF_PART  (OFF_ORAW + N_NODES * HC)           // partial sums [1024]
#define OFF_MEAN  (OFF_PART + 1024)                   // mean scalar [1]
#define WS_FLOATS (OFF_MEAN + 1)

// ---------------- edge_attr mean (deterministic 2-stage) ----------------
__global__ void mean_part_kernel(const float* __restrict__ ea, float* __restrict__ part) {
    __shared__ float sd[256];
    int t = threadIdx.x;
    float s = 0.f;
    for (int i = blockIdx.x * 256 + t; i < N_EDGES; i += 1024 * 256) s += ea[i];
    sd[t] = s; __syncthreads();
    for (int w = 128; w > 0; w >>= 1) { if (t < w) sd[t] += sd[t + w]; __syncthreads(); }
    if (t == 0) part[blockIdx.x] = sd[0];
}

__global__ void mean_final_kernel(const float* __restrict__ part, float* __restrict__ mean_out) {
    __shared__ float sd[256];
    int t = threadIdx.x;
    float s = part[t] + part[t + 256] + part[t + 512] + part[t + 768];
    sd[t] = s; __syncthreads();
    for (int w = 128; w > 0; w >>= 1) { if (t < w) sd[t] += sd[t + w]; __syncthreads(); }
    if (t == 0) mean_out[0] = sd[0] / (float)N_EDGES;
}

// ---------------- fused GEMM: [x_l | x_r | proj] = x @ [W_l|W_r|W_proj]^T ----------------
// M=50000, Nout=544 (256+256+32), K=128.  64x64 tile, K split in 2 subtiles of 64,
// 256 threads, 4x4 micro-tile.  Unroll capped to keep VGPR < 128 (round-1 spilled at 256).
#define BM 64
#define BN 64
#define BK 64
#define LDSB 68   // 64+4 floats: float4-aligned pad, breaks power-of-2 bank stride

__global__ __launch_bounds__(256) void gemm_xw_kernel(
    const float* __restrict__ x,
    const float* __restrict__ Wl, const float* __restrict__ Wr, const float* __restrict__ Wproj,
    float* __restrict__ xl, float* __restrict__ xr, float* __restrict__ proj)
{
    __shared__ float As[BM * LDSB];   // 17.4 KB
    __shared__ float Bs[BN * LDSB];   // 17.4 KB  (total 34.8 KB -> 4 blocks/CU)
    const int m0 = blockIdx.x * BM;
    const int n0 = blockIdx.y * BN;
    const int t = threadIdx.x;
    const int tr = t >> 4;   // 0..15 -> rows 4*tr+i
    const int tc = t & 15;   // 0..15 -> cols tc+16*j

    float acc[4][4] = {};

    for (int kt = 0; kt < 2; ++kt) {
        // stage A subtile (64 rows x 64 k) as float4: 1024 chunks / 256 threads
        #pragma unroll
        for (int cc = 0; cc < 4; ++cc) {
            int ch = t + cc * 256;
            int r = ch >> 4, c4 = ch & 15;
            int row = m0 + r;
            float4 v = make_float4(0.f, 0.f, 0.f, 0.f);
            if (row < N_NODES) v = ((const float4*)(x + (size_t)row * IN_DIM))[kt * 16 + c4];
            *((float4*)(As + r * LDSB + c4 * 4)) = v;
        }
        // stage B subtile (combined weight rows n0..n0+63, k-cols kt*64..)
        #pragma unroll
        for (int cc = 0; cc < 4; ++cc) {
            int ch = t + cc * 256;
            int r = ch >> 4, c4 = ch & 15;
            int j = n0 + r;
            float4 v = make_float4(0.f, 0.f, 0.f, 0.f);
            if (j < 256)      v = ((const float4*)(Wl + (size_t)j * IN_DIM))[kt * 16 + c4];
            else if (j < 512) v = ((const float4*)(Wr + (size_t)(j - 256) * IN_DIM))[kt * 16 + c4];
            else if (j < 544) v = ((const float4*)(Wproj + (size_t)(j - 512) * IN_DIM))[kt * 16 + c4];
            *((float4*)(Bs + r * LDSB + c4 * 4)) = v;
        }
        __syncthreads();

        #pragma unroll 4
        for (int k4 = 0; k4 < 16; ++k4) {
            float4 a[4], b[4];
            #pragma unroll
            for (int i = 0; i < 4; ++i) a[i] = *((const float4*)(As + (4 * tr + i) * LDSB + k4 * 4));
            #pragma unroll
            for (int j = 0; j < 4; ++j) b[j] = *((const float4*)(Bs + (tc + 16 * j) * LDSB + k4 * 4));
            #pragma unroll
            for (int i = 0; i < 4; ++i)
                #pragma unroll
                for (int j = 0; j < 4; ++j)
                    acc[i][j] += a[i].x * b[j].x + a[i].y * b[j].y + a[i].z * b[j].z + a[i].w * b[j].w;
        }
        __syncthreads();
    }

    #pragma unroll
    for (int i = 0; i < 4; ++i) {
        int row = m0 + 4 * tr + i;
        if (row >= N_NODES) continue;
        #pragma unroll
        for (int j = 0; j < 4; ++j) {
            int col = n0 + tc + 16 * j;
            float v = acc[i][j];
            if (col < 256)      xl[(size_t)row * HC + col] = v;
            else if (col < 512) xr[(size_t)row * HC + (col - 256)] = v;
            else if (col < 544) proj[(size_t)row * C_CH + (col - 512)] = v;
        }
    }
}

// ---------------- edge pass: logits + exp + fused atomic aggregation ----------------
// one wave (64 lanes) per edge; 4 edges per 256-thread block
__global__ __launch_bounds__(256) void edge_kernel(
    const int* __restrict__ ei, const float* __restrict__ edge_attr,
    const float* __restrict__ We, const float* __restrict__ att,
    const float* __restrict__ xl, const float* __restrict__ xr,
    const float* __restrict__ mean_attr,
    float* __restrict__ aexp_out, float* __restrict__ denom, float* __restrict__ oraw)
{
    const int lane = threadIdx.x & 63;
    const int e = blockIdx.x * 4 + (threadIdx.x >> 6);
    if (e >= EN_TOT) return;

    int s, d; float eav;
    if (e < N_EDGES) { s = ei[e]; d = ei[N_EDGES + e]; eav = edge_attr[e]; }
    else { s = e - N_EDGES; d = s; eav = mean_attr[0]; }

    const float4 we = ((const float4*)We)[lane];     // W_e[4l..4l+3]
    const float4 at = ((const float4*)att)[lane];    // att flat [8*32]
    const float4 vl = ((const float4*)(xl + (size_t)s * HC))[lane];
    const float4 vr = ((const float4*)(xr + (size_t)d * HC))[lane];

    float m0 = vl.x + vr.x + eav * we.x;
    float m1 = vl.y + vr.y + eav * we.y;
    float m2 = vl.z + vr.z + eav * we.z;
    float m3 = vl.w + vr.w + eav * we.w;
    m0 = (m0 > 0.f) ? m0 : NEG_SLOPE * m0;
    m1 = (m1 > 0.f) ? m1 : NEG_SLOPE * m1;
    m2 = (m2 > 0.f) ? m2 : NEG_SLOPE * m2;
    m3 = (m3 > 0.f) ? m3 : NEG_SLOPE * m3;
    float ssum = m0 * at.x + m1 * at.y + m2 * at.z + m3 * at.w;

    // reduce over the 8 lanes of this head (lanes 8h..8h+7)
    ssum += __shfl_xor(ssum, 1);
    ssum += __shfl_xor(ssum, 2);
    ssum += __shfl_xor(ssum, 4);

    const float aex = expf(ssum);   // no max-subtraction: logits are O(1), exp-safe in fp32
    const int h = lane >> 3;
    if ((lane & 7) == 0) {
        aexp_out[(size_t)e * H_HEADS + h] = aex;
        unsafeAtomicAdd(&denom[(size_t)d * H_HEADS + h], aex);
    }

    float* dstp = oraw + (size_t)d * HC + lane * 4;
    unsafeAtomicAdd(dstp + 0, aex * vl.x);
    unsafeAtomicAdd(dstp + 1, aex * vl.y);
    unsafeAtomicAdd(dstp + 2, aex * vl.z);
    unsafeAtomicAdd(dstp + 3, aex * vl.w);
}

// ---------------- node finalize: mean over heads, relu, +bias, +proj ----------------
__global__ __launch_bounds__(256) void finalize_kernel(
    const float* __restrict__ oraw, const float* __restrict__ denom,
    const float* __restrict__ proj, const float* __restrict__ bias,
    float* __restrict__ xnew)
{
    int idx = blockIdx.x * 256 + threadIdx.x;   // n*32 + c
    if (idx >= N_NODES * C_CH) return;
    int n = idx >> 5, c = idx & 31;
    float acc = 0.f;
    #pragma unroll
    for (int h = 0; h < H_HEADS; ++h)
        acc += oraw[(size_t)n * HC + h * C_CH + c] / denom[(size_t)n * H_HEADS + h];
    acc = acc * (1.f / H_HEADS) + bias[c];
    xnew[idx] = fmaxf(acc, 0.f) + proj[idx];
}

// ---------------- normalized alpha write ----------------
__global__ __launch_bounds__(256) void alpha_kernel(
    const int* __restrict__ ei, const float* __restrict__ aexp,
    const float* __restrict__ denom, float* __restrict__ alpha_out)
{
    int idx = blockIdx.x * 256 + threadIdx.x;   // e*8 + h
    if (idx >= EN_TOT * H_HEADS) return;
    int e = idx >> 3, h = idx & 7;
    int d = (e < N_EDGES) ? ei[N_EDGES + e] : (e - N_EDGES);
    alpha_out[idx] = aexp[idx] / denom[(size_t)d * H_HEADS + h];
}

extern "C" void kernel_launch(void* const* d_in, const int* in_sizes, int n_in,
                              void* d_out, int out_size, void* d_ws, size_t ws_size,
                              hipStream_t stream) {
    const float* x         = (const float*)d_in[0];
    const int*   ei        = (const int*)d_in[1];
    const float* edge_attr = (const float*)d_in[2];
    // d_in[3] = batch (unused)
    const float* Wl        = (const float*)d_in[4];
    const float* Wr        = (const float*)d_in[5];
    const float* We        = (const float*)d_in[6];
    const float* att       = (const float*)d_in[7];
    const float* bias      = (const float*)d_in[8];
    const float* Wproj     = (const float*)d_in[9];

    float* ws    = (float*)d_ws;
    float* xl    = ws + OFF_XL;
    float* xr    = ws + OFF_XR;
    float* proj  = ws + OFF_PROJ;
    float* aexp  = ws + OFF_AEXP;
    float* denom = ws + OFF_DENOM;
    float* oraw  = ws + OFF_ORAW;
    float* part  = ws + OFF_PART;
    float* meanp = ws + OFF_MEAN;

    float* out_xnew  = (float*)d_out;
    float* out_alpha = (float*)d_out + (size_t)N_NODES * C_CH;

    // zero denom + oraw (contiguous)
    hipMemsetAsync(denom, 0, (size_t)(N_NODES * H_HEADS + N_NODES * HC) * sizeof(float), stream);

    mean_part_kernel<<<1024, 256, 0, stream>>>(edge_attr, part);
    mean_final_kernel<<<1, 256, 0, stream>>>(part, meanp);

    dim3 ggrid((N_NODES + BM - 1) / BM, (544 + BN - 1) / BN);
    gemm_xw_kernel<<<ggrid, 256, 0, stream>>>(x, Wl, Wr, Wproj, xl, xr, proj);

    edge_kernel<<<EN_TOT / 4, 256, 0, stream>>>(ei, edge_attr, We, att, xl, xr, meanp,
                                                aexp, denom, oraw);

    finalize_kernel<<<(N_NODES * C_CH) / 256, 256, 0, stream>>>(oraw, denom, proj, bias, out_xnew);

    alpha_kernel<<<(EN_TOT * H_HEADS + 255) / 256, 256, 0, stream>>>(ei, aexp, denom, out_alpha);
}

// Round 3
// 371.326 us; speedup vs baseline: 15.3228x; 4.5368x over previous
//
#include <hip/hip_runtime.h>
#include <math.h>

#define N_NODES 50000
#define N_EDGES 400000
#define EN_TOT  450000
#define IN_DIM  128
#define H_HEADS 8
#define C_CH    32
#define HC      256
#define NEG_SLOPE 0.2f

// ---------------- workspace layout ----------------
// floats
#define OFF_XL    0                                   // x_l  [N, 256]
#define OFF_XR    (OFF_XL + N_NODES * HC)             // x_r  [N, 256]
#define OFF_PROJ  (OFF_XR + N_NODES * HC)             // proj [N, 32]
#define OFF_AEXP  (OFF_PROJ + N_NODES * C_CH)         // aexp [E+N, 8]
#define OFF_DENOM (OFF_AEXP + EN_TOT * H_HEADS)       // denom[N, 8]
#define OFF_PART  (OFF_DENOM + N_NODES * H_HEADS)     // partial sums [1024]
#define OFF_MEAN  (OFF_PART + 1024)                   // mean scalar [1]
#define OFF_CEAV  (OFF_MEAN + 1)                      // csr_eav [E+N]
// ints (carved from float ws, 4B each)
#define OFF_CSRC  (OFF_CEAV + EN_TOT)                 // csr_src [E+N]
#define OFF_CEID  (OFF_CSRC + EN_TOT)                 // csr_eid [E+N]
#define OFF_DEG   (OFF_CEID + EN_TOT)                 // deg     [N]
#define OFF_OFFS  (OFF_DEG + N_NODES)                 // offs    [N+1]
#define OFF_CUR   (OFF_OFFS + N_NODES + 1)            // cursor  [N]

// ---------------- edge_attr mean (deterministic 2-stage) ----------------
__global__ void mean_part_kernel(const float* __restrict__ ea, float* __restrict__ part) {
    __shared__ float sd[256];
    int t = threadIdx.x;
    float s = 0.f;
    for (int i = blockIdx.x * 256 + t; i < N_EDGES; i += 1024 * 256) s += ea[i];
    sd[t] = s; __syncthreads();
    for (int w = 128; w > 0; w >>= 1) { if (t < w) sd[t] += sd[t + w]; __syncthreads(); }
    if (t == 0) part[blockIdx.x] = sd[0];
}

__global__ void mean_final_kernel(const float* __restrict__ part, float* __restrict__ mean_out) {
    __shared__ float sd[256];
    int t = threadIdx.x;
    float s = part[t] + part[t + 256] + part[t + 512] + part[t + 768];
    sd[t] = s; __syncthreads();
    for (int w = 128; w > 0; w >>= 1) { if (t < w) sd[t] += sd[t + w]; __syncthreads(); }
    if (t == 0) mean_out[0] = sd[0] / (float)N_EDGES;
}

// ---------------- CSR build: histogram -> scan -> scatter ----------------
__global__ __launch_bounds__(256) void hist_kernel(const int* __restrict__ ei, int* __restrict__ deg) {
    int e = blockIdx.x * 256 + threadIdx.x;
    if (e >= EN_TOT) return;
    int d = (e < N_EDGES) ? ei[N_EDGES + e] : (e - N_EDGES);
    atomicAdd(&deg[d], 1);
}

__global__ __launch_bounds__(1024) void prefix_kernel(const int* __restrict__ deg, int* __restrict__ offs) {
    __shared__ int lds[1024];
    const int CH = (N_NODES + 1023) / 1024;   // 49
    int t = threadIdx.x;
    int lo = t * CH, hi = lo + CH; if (hi > N_NODES) hi = N_NODES; if (lo > N_NODES) lo = N_NODES;
    int s = 0;
    for (int i = lo; i < hi; ++i) s += deg[i];
    lds[t] = s; __syncthreads();
    for (int ofs = 1; ofs < 1024; ofs <<= 1) {
        int v = (t >= ofs) ? lds[t - ofs] : 0;
        __syncthreads();
        lds[t] += v;
        __syncthreads();
    }
    int run = lds[t] - s;   // exclusive prefix of this chunk
    for (int i = lo; i < hi; ++i) { offs[i] = run; run += deg[i]; }
    if (t == 1023) offs[N_NODES] = run;
}

__global__ __launch_bounds__(256) void cursor_kernel(const int* __restrict__ offs, int* __restrict__ cur) {
    int i = blockIdx.x * 256 + threadIdx.x;
    if (i < N_NODES) cur[i] = offs[i];
}

__global__ __launch_bounds__(256) void scatter_kernel(
    const int* __restrict__ ei, const float* __restrict__ edge_attr,
    const float* __restrict__ mean_attr, int* __restrict__ cur,
    int* __restrict__ csr_src, int* __restrict__ csr_eid, float* __restrict__ csr_eav)
{
    int e = blockIdx.x * 256 + threadIdx.x;
    if (e >= EN_TOT) return;
    int s, d; float eav;
    if (e < N_EDGES) { s = ei[e]; d = ei[N_EDGES + e]; eav = edge_attr[e]; }
    else { s = e - N_EDGES; d = s; eav = mean_attr[0]; }
    int pos = atomicAdd(&cur[d], 1);
    csr_src[pos] = s;
    csr_eid[pos] = e;
    csr_eav[pos] = eav;
}

// ---------------- fused GEMM: [x_l | x_r | proj] = x @ [W_l|W_r|W_proj]^T ----------------
#define BM 64
#define BN 64
#define LDSB 68   // 64+4 floats: float4-aligned pad, breaks power-of-2 bank stride

__global__ __launch_bounds__(256) void gemm_xw_kernel(
    const float* __restrict__ x,
    const float* __restrict__ Wl, const float* __restrict__ Wr, const float* __restrict__ Wproj,
    float* __restrict__ xl, float* __restrict__ xr, float* __restrict__ proj)
{
    __shared__ float As[BM * LDSB];   // 17.4 KB
    __shared__ float Bs[BN * LDSB];   // 17.4 KB
    const int m0 = blockIdx.x * BM;
    const int n0 = blockIdx.y * BN;
    const int t = threadIdx.x;
    const int tr = t >> 4;
    const int tc = t & 15;

    float acc[4][4] = {};

    for (int kt = 0; kt < 2; ++kt) {
        #pragma unroll
        for (int cc = 0; cc < 4; ++cc) {
            int ch = t + cc * 256;
            int r = ch >> 4, c4 = ch & 15;
            int row = m0 + r;
            float4 v = make_float4(0.f, 0.f, 0.f, 0.f);
            if (row < N_NODES) v = ((const float4*)(x + (size_t)row * IN_DIM))[kt * 16 + c4];
            *((float4*)(As + r * LDSB + c4 * 4)) = v;
        }
        #pragma unroll
        for (int cc = 0; cc < 4; ++cc) {
            int ch = t + cc * 256;
            int r = ch >> 4, c4 = ch & 15;
            int j = n0 + r;
            float4 v = make_float4(0.f, 0.f, 0.f, 0.f);
            if (j < 256)      v = ((const float4*)(Wl + (size_t)j * IN_DIM))[kt * 16 + c4];
            else if (j < 512) v = ((const float4*)(Wr + (size_t)(j - 256) * IN_DIM))[kt * 16 + c4];
            else if (j < 544) v = ((const float4*)(Wproj + (size_t)(j - 512) * IN_DIM))[kt * 16 + c4];
            *((float4*)(Bs + r * LDSB + c4 * 4)) = v;
        }
        __syncthreads();

        #pragma unroll 4
        for (int k4 = 0; k4 < 16; ++k4) {
            float4 a[4], b[4];
            #pragma unroll
            for (int i = 0; i < 4; ++i) a[i] = *((const float4*)(As + (4 * tr + i) * LDSB + k4 * 4));
            #pragma unroll
            for (int j = 0; j < 4; ++j) b[j] = *((const float4*)(Bs + (tc + 16 * j) * LDSB + k4 * 4));
            #pragma unroll
            for (int i = 0; i < 4; ++i)
                #pragma unroll
                for (int j = 0; j < 4; ++j)
                    acc[i][j] += a[i].x * b[j].x + a[i].y * b[j].y + a[i].z * b[j].z + a[i].w * b[j].w;
        }
        __syncthreads();
    }

    #pragma unroll
    for (int i = 0; i < 4; ++i) {
        int row = m0 + 4 * tr + i;
        if (row >= N_NODES) continue;
        #pragma unroll
        for (int j = 0; j < 4; ++j) {
            int col = n0 + tc + 16 * j;
            float v = acc[i][j];
            if (col < 256)      xl[(size_t)row * HC + col] = v;
            else if (col < 512) xr[(size_t)row * HC + (col - 256)] = v;
            else if (col < 544) proj[(size_t)row * C_CH + (col - 512)] = v;
        }
    }
}

// ---------------- fused node aggregation: logits + exp + weighted sum + epilogue ----------------
// one wave per node; atomic-free. Numerator and denominator accumulate in registers
// (valid because softmax here is computed without max-subtraction; logits are O(1)).
__global__ __launch_bounds__(256) void node_agg_kernel(
    const int* __restrict__ offs, const int* __restrict__ csr_src,
    const int* __restrict__ csr_eid, const float* __restrict__ csr_eav,
    const float* __restrict__ We, const float* __restrict__ att,
    const float* __restrict__ xl, const float* __restrict__ xr,
    const float* __restrict__ proj, const float* __restrict__ bias,
    float* __restrict__ aexp_out, float* __restrict__ denom, float* __restrict__ xnew)
{
    const int lane = threadIdx.x & 63;
    const int d = blockIdx.x * 4 + (threadIdx.x >> 6);
    if (d >= N_NODES) return;

    const float4 we = ((const float4*)We)[lane];    // W_e[:,0] slice for this lane's 4 channels
    const float4 at = ((const float4*)att)[lane];
    const float4 vr = ((const float4*)(xr + (size_t)d * HC))[lane];
    const int h = lane >> 3;

    float4 acc = make_float4(0.f, 0.f, 0.f, 0.f);
    float den = 0.f;

    int i = offs[d];
    const int end = offs[d + 1];

    // 1-deep software pipeline on the x_l gather
    int s0 = 0, e0 = 0; float ea0 = 0.f; float4 vl0 = make_float4(0.f, 0.f, 0.f, 0.f);
    if (i < end) {
        s0 = csr_src[i]; e0 = csr_eid[i]; ea0 = csr_eav[i];
        vl0 = ((const float4*)(xl + (size_t)s0 * HC))[lane];
    }
    while (i < end) {
        const int j = i + 1;
        int s1 = 0, e1 = 0; float ea1 = 0.f; float4 vl1 = make_float4(0.f, 0.f, 0.f, 0.f);
        if (j < end) {
            s1 = csr_src[j]; e1 = csr_eid[j]; ea1 = csr_eav[j];
            vl1 = ((const float4*)(xl + (size_t)s1 * HC))[lane];
        }

        float m0 = vl0.x + vr.x + ea0 * we.x;
        float m1 = vl0.y + vr.y + ea0 * we.y;
        float m2 = vl0.z + vr.z + ea0 * we.z;
        float m3 = vl0.w + vr.w + ea0 * we.w;
        m0 = (m0 > 0.f) ? m0 : NEG_SLOPE * m0;
        m1 = (m1 > 0.f) ? m1 : NEG_SLOPE * m1;
        m2 = (m2 > 0.f) ? m2 : NEG_SLOPE * m2;
        m3 = (m3 > 0.f) ? m3 : NEG_SLOPE * m3;
        float t = m0 * at.x + m1 * at.y + m2 * at.z + m3 * at.w;
        t += __shfl_xor(t, 1);
        t += __shfl_xor(t, 2);
        t += __shfl_xor(t, 4);
        const float aex = __expf(t);

        if ((lane & 7) == 0) aexp_out[(size_t)e0 * H_HEADS + h] = aex;
        acc.x += aex * vl0.x; acc.y += aex * vl0.y;
        acc.z += aex * vl0.z; acc.w += aex * vl0.w;
        den += aex;

        s0 = s1; e0 = e1; ea0 = ea1; vl0 = vl1; i = j;
    }

    if ((lane & 7) == 0) denom[(size_t)d * H_HEADS + h] = den;

    // head mean: scale by 1/den, reduce across the 8 head groups (stride-8 lanes)
    const float inv = 1.f / den;
    acc.x *= inv; acc.y *= inv; acc.z *= inv; acc.w *= inv;
    #pragma unroll
    for (int mask = 8; mask <= 32; mask <<= 1) {
        acc.x += __shfl_xor(acc.x, mask);
        acc.y += __shfl_xor(acc.y, mask);
        acc.z += __shfl_xor(acc.z, mask);
        acc.w += __shfl_xor(acc.w, mask);
    }
    if (lane < 8) {
        const float4 bi = ((const float4*)bias)[lane];
        const float4 pr = ((const float4*)(proj + (size_t)d * C_CH))[lane];
        float4 r;
        r.x = fmaxf(acc.x * 0.125f + bi.x, 0.f) + pr.x;
        r.y = fmaxf(acc.y * 0.125f + bi.y, 0.f) + pr.y;
        r.z = fmaxf(acc.z * 0.125f + bi.z, 0.f) + pr.z;
        r.w = fmaxf(acc.w * 0.125f + bi.w, 0.f) + pr.w;
        ((float4*)(xnew + (size_t)d * C_CH))[lane] = r;
    }
}

// ---------------- normalized alpha write ----------------
__global__ __launch_bounds__(256) void alpha_kernel(
    const int* __restrict__ ei, const float* __restrict__ aexp,
    const float* __restrict__ denom, float* __restrict__ alpha_out)
{
    int idx = blockIdx.x * 256 + threadIdx.x;   // e*8 + h
    if (idx >= EN_TOT * H_HEADS) return;
    int e = idx >> 3, h = idx & 7;
    int d = (e < N_EDGES) ? ei[N_EDGES + e] : (e - N_EDGES);
    alpha_out[idx] = aexp[idx] / denom[(size_t)d * H_HEADS + h];
}

extern "C" void kernel_launch(void* const* d_in, const int* in_sizes, int n_in,
                              void* d_out, int out_size, void* d_ws, size_t ws_size,
                              hipStream_t stream) {
    const float* x         = (const float*)d_in[0];
    const int*   ei        = (const int*)d_in[1];
    const float* edge_attr = (const float*)d_in[2];
    // d_in[3] = batch (unused)
    const float* Wl        = (const float*)d_in[4];
    const float* Wr        = (const float*)d_in[5];
    const float* We        = (const float*)d_in[6];
    const float* att       = (const float*)d_in[7];
    const float* bias      = (const float*)d_in[8];
    const float* Wproj     = (const float*)d_in[9];

    float* ws    = (float*)d_ws;
    float* xl    = ws + OFF_XL;
    float* xr    = ws + OFF_XR;
    float* proj  = ws + OFF_PROJ;
    float* aexp  = ws + OFF_AEXP;
    float* denom = ws + OFF_DENOM;
    float* part  = ws + OFF_PART;
    float* meanp = ws + OFF_MEAN;
    float* ceav  = ws + OFF_CEAV;
    int*   csrc  = (int*)(ws + OFF_CSRC);
    int*   ceid  = (int*)(ws + OFF_CEID);
    int*   deg   = (int*)(ws + OFF_DEG);
    int*   offs  = (int*)(ws + OFF_OFFS);
    int*   cur   = (int*)(ws + OFF_CUR);

    float* out_xnew  = (float*)d_out;
    float* out_alpha = (float*)d_out + (size_t)N_NODES * C_CH;

    hipMemsetAsync(deg, 0, N_NODES * sizeof(int), stream);

    mean_part_kernel<<<1024, 256, 0, stream>>>(edge_attr, part);
    mean_final_kernel<<<1, 256, 0, stream>>>(part, meanp);

    hist_kernel<<<(EN_TOT + 255) / 256, 256, 0, stream>>>(ei, deg);
    prefix_kernel<<<1, 1024, 0, stream>>>(deg, offs);
    cursor_kernel<<<(N_NODES + 255) / 256, 256, 0, stream>>>(offs, cur);
    scatter_kernel<<<(EN_TOT + 255) / 256, 256, 0, stream>>>(ei, edge_attr, meanp, cur,
                                                             csrc, ceid, ceav);

    dim3 ggrid((N_NODES + BM - 1) / BM, (544 + BN - 1) / BN);
    gemm_xw_kernel<<<ggrid, 256, 0, stream>>>(x, Wl, Wr, Wproj, xl, xr, proj);

    node_agg_kernel<<<(N_NODES + 3) / 4, 256, 0, stream>>>(offs, csrc, ceid, ceav,
                                                           We, att, xl, xr, proj, bias,
                                                           aexp, denom, out_xnew);

    alpha_kernel<<<(EN_TOT * H_HEADS + 255) / 256, 256, 0, stream>>>(ei, aexp, denom, out_alpha);
}

// Round 4
// 319.145 us; speedup vs baseline: 17.8282x; 1.1635x over previous
//
#include <hip/hip_runtime.h>
#include <math.h>

#define N_NODES 50000
#define N_EDGES 400000
#define EN_TOT  450000
#define IN_DIM  128
#define H_HEADS 8
#define C_CH    32
#define HC      256
#define NEG_SLOPE 0.2f

typedef __attribute__((ext_vector_type(8))) short bf16x8;
typedef __attribute__((ext_vector_type(4))) float f32x4;

// ---------------- workspace layout ----------------
// floats
#define OFF_XL    0                                   // x_l  [N, 256]
#define OFF_XR    (OFF_XL + N_NODES * HC)             // x_r  [N, 256]
#define OFF_PROJ  (OFF_XR + N_NODES * HC)             // proj [N, 32]
#define OFF_AEXP  (OFF_PROJ + N_NODES * C_CH)         // aexp [E+N, 8]  (aliased: xbf during GEMM phase)
#define OFF_DENOM (OFF_AEXP + EN_TOT * H_HEADS)       // denom[N, 8]   (aliased: wcat during GEMM phase)
#define OFF_PART  (OFF_DENOM + N_NODES * H_HEADS)     // partial sums [1024]
#define OFF_MEAN  (OFF_PART + 1024)                   // mean scalar [1]
#define OFF_CEAV  (OFF_MEAN + 1)                      // csr_eav [E+N]
// ints (carved from float ws, 4B each)
#define OFF_CSRC  (OFF_CEAV + EN_TOT)                 // csr_src [E+N]
#define OFF_CEID  (OFF_CSRC + EN_TOT)                 // csr_eid [E+N]
#define OFF_DEG   (OFF_CEID + EN_TOT)                 // deg     [N]
#define OFF_OFFS  (OFF_DEG + N_NODES)                 // offs    [N+1]
#define OFF_CUR   (OFF_OFFS + N_NODES + 1)            // cursor  [N]

// ---------------- fp32 -> bf16 (RNE) ----------------
__device__ __forceinline__ unsigned f2bf(float f) {
    unsigned u = __float_as_uint(f);
    u += 0x7fffu + ((u >> 16) & 1u);
    return u >> 16;
}

// convert x [50000,128] and Wcat=[Wl;Wr;Wproj] [544,128] to bf16
#define XCHUNKS 800000            // 50000*128/8
#define WCHUNKS 8704              // 544*128/8
__global__ __launch_bounds__(256) void convert_kernel(
    const float* __restrict__ x,
    const float* __restrict__ Wl, const float* __restrict__ Wr, const float* __restrict__ Wproj,
    unsigned short* __restrict__ xbf, unsigned short* __restrict__ wcat)
{
    int t = blockIdx.x * 256 + threadIdx.x;
    const float* src; uint4* dst;
    if (t < XCHUNKS) {
        src = x + (size_t)t * 8;
        dst = (uint4*)xbf + t;
    } else if (t < XCHUNKS + WCHUNKS) {
        int c = t - XCHUNKS;
        int j = (c * 8) >> 7, k = (c * 8) & 127;
        src = (j < 256 ? Wl + (size_t)j * 128 : (j < 512 ? Wr + (size_t)(j - 256) * 128
                                                         : Wproj + (size_t)(j - 512) * 128)) + k;
        dst = (uint4*)wcat + c;
    } else return;
    float4 a = ((const float4*)src)[0];
    float4 b = ((const float4*)src)[1];
    uint4 o;
    o.x = f2bf(a.x) | (f2bf(a.y) << 16);
    o.y = f2bf(a.z) | (f2bf(a.w) << 16);
    o.z = f2bf(b.x) | (f2bf(b.y) << 16);
    o.w = f2bf(b.z) | (f2bf(b.w) << 16);
    *dst = o;
}

// ---------------- fused hist (over dst) + edge_attr partial sums ----------------
__global__ __launch_bounds__(256) void hist_mean_kernel(
    const int* __restrict__ ei, const float* __restrict__ ea,
    int* __restrict__ deg, float* __restrict__ part)
{
    __shared__ float sd[256];
    int t = threadIdx.x;
    int g = blockIdx.x * 256 + t;
    float s = 0.f;
    for (int i = g; i < N_EDGES; i += 1024 * 256) s += ea[i];
    for (int i = g; i < EN_TOT; i += 1024 * 256) {
        int d = (i < N_EDGES) ? ei[N_EDGES + i] : (i - N_EDGES);
        atomicAdd(&deg[d], 1);
    }
    sd[t] = s; __syncthreads();
    for (int w = 128; w > 0; w >>= 1) { if (t < w) sd[t] += sd[t + w]; __syncthreads(); }
    if (t == 0) part[blockIdx.x] = sd[0];
}

__global__ void mean_final_kernel(const float* __restrict__ part, float* __restrict__ mean_out) {
    __shared__ float sd[256];
    int t = threadIdx.x;
    float s = part[t] + part[t + 256] + part[t + 512] + part[t + 768];
    sd[t] = s; __syncthreads();
    for (int w = 128; w > 0; w >>= 1) { if (t < w) sd[t] += sd[t + w]; __syncthreads(); }
    if (t == 0) mean_out[0] = sd[0] / (float)N_EDGES;
}

__global__ __launch_bounds__(1024) void prefix_kernel(const int* __restrict__ deg,
                                                      int* __restrict__ offs, int* __restrict__ cur) {
    __shared__ int lds[1024];
    const int CH = (N_NODES + 1023) / 1024;   // 49
    int t = threadIdx.x;
    int lo = t * CH, hi = lo + CH; if (hi > N_NODES) hi = N_NODES; if (lo > N_NODES) lo = N_NODES;
    int s = 0;
    for (int i = lo; i < hi; ++i) s += deg[i];
    lds[t] = s; __syncthreads();
    for (int ofs = 1; ofs < 1024; ofs <<= 1) {
        int v = (t >= ofs) ? lds[t - ofs] : 0;
        __syncthreads();
        lds[t] += v;
        __syncthreads();
    }
    int run = lds[t] - s;   // exclusive prefix of this chunk
    for (int i = lo; i < hi; ++i) { offs[i] = run; cur[i] = run; run += deg[i]; }
    if (t == 1023) offs[N_NODES] = run;
}

__global__ __launch_bounds__(256) void scatter_kernel(
    const int* __restrict__ ei, const float* __restrict__ edge_attr,
    const float* __restrict__ mean_attr, int* __restrict__ cur,
    int* __restrict__ csr_src, int* __restrict__ csr_eid, float* __restrict__ csr_eav)
{
    int e = blockIdx.x * 256 + threadIdx.x;
    if (e >= EN_TOT) return;
    int s, d; float eav;
    if (e < N_EDGES) { s = ei[e]; d = ei[N_EDGES + e]; eav = edge_attr[e]; }
    else { s = e - N_EDGES; d = s; eav = mean_attr[0]; }
    int pos = atomicAdd(&cur[d], 1);
    csr_src[pos] = s;
    csr_eid[pos] = e;
    csr_eav[pos] = eav;
}

// ---------------- MFMA GEMM: [x_l | x_r | proj] = x @ Wcat^T (bf16 in, fp32 out) ----------------
// 128x64 tile, full K=128 in LDS (48 KB -> 3 blocks/CU). 4 waves in 2x2 grid,
// each wave 64x32 output = 4x2 fragments of 16x16x32. XOR swizzle (row&7)<<4 on
// 16B granules kills the stride-256B bank conflict (T2).
#define GM 128
#define GN 64

__global__ __launch_bounds__(256) void gemm_mfma_kernel(
    const unsigned short* __restrict__ xbf, const unsigned short* __restrict__ wcat,
    float* __restrict__ xl, float* __restrict__ xr, float* __restrict__ proj)
{
    __shared__ unsigned short As[GM * 128];   // 32 KB
    __shared__ unsigned short Bs[GN * 128];   // 16 KB
    const int t = threadIdx.x;
    const int m0 = blockIdx.x * GM;
    const int n0 = blockIdx.y * GN;

    // stage A: 2048 16B-chunks (row-major [128][128] bf16, swizzled)
    #pragma unroll
    for (int cc = 0; cc < 8; ++cc) {
        int c = t + cc * 256;
        int r = c >> 4;
        int k0 = (c & 15) * 8;
        int row = m0 + r;
        uint4 v = make_uint4(0, 0, 0, 0);
        if (row < N_NODES) v = *((const uint4*)(xbf + (size_t)row * 128 + k0));
        int byte = (r * 256 + k0 * 2) ^ ((r & 7) << 4);
        *((uint4*)((char*)As + byte)) = v;
    }
    // stage B: 1024 chunks ([64][128] bf16 rows n0..n0+63)
    #pragma unroll
    for (int cc = 0; cc < 4; ++cc) {
        int c = t + cc * 256;
        int r = c >> 4;
        int k0 = (c & 15) * 8;
        int j = n0 + r;
        uint4 v = make_uint4(0, 0, 0, 0);
        if (j < 544) v = *((const uint4*)(wcat + (size_t)j * 128 + k0));
        int byte = (r * 256 + k0 * 2) ^ ((r & 7) << 4);
        *((uint4*)((char*)Bs + byte)) = v;
    }
    __syncthreads();

    const int wid = t >> 6, lane = t & 63;
    const int wr = wid >> 1, wc = wid & 1;
    const int lrow = lane & 15;
    const int kgrp = (lane >> 4) * 8;

    f32x4 acc[4][2] = {};
    #pragma unroll
    for (int kk = 0; kk < 4; ++kk) {
        bf16x8 a[4], b[2];
        #pragma unroll
        for (int fm = 0; fm < 4; ++fm) {
            int r = wr * 64 + fm * 16 + lrow;
            int byte = (r * 256 + (kk * 32 + kgrp) * 2) ^ ((r & 7) << 4);
            a[fm] = *((const bf16x8*)((const char*)As + byte));
        }
        #pragma unroll
        for (int fn = 0; fn < 2; ++fn) {
            int r = wc * 32 + fn * 16 + lrow;
            int byte = (r * 256 + (kk * 32 + kgrp) * 2) ^ ((r & 7) << 4);
            b[fn] = *((const bf16x8*)((const char*)Bs + byte));
        }
        #pragma unroll
        for (int fm = 0; fm < 4; ++fm)
            #pragma unroll
            for (int fn = 0; fn < 2; ++fn)
                acc[fm][fn] = __builtin_amdgcn_mfma_f32_16x16x32_bf16(a[fm], b[fn], acc[fm][fn], 0, 0, 0);
    }

    // epilogue: C[row = (lane>>4)*4 + reg, col = lane&15]  (m89-verified)
    const int crow0 = (lane >> 4) * 4;
    const int ccol = lane & 15;
    #pragma unroll
    for (int fm = 0; fm < 4; ++fm) {
        #pragma unroll
        for (int fn = 0; fn < 2; ++fn) {
            #pragma unroll
            for (int r = 0; r < 4; ++r) {
                int row = m0 + wr * 64 + fm * 16 + crow0 + r;
                int col = n0 + wc * 32 + fn * 16 + ccol;
                if (row >= N_NODES) continue;
                float v = acc[fm][fn][r];
                if (col < 256)      xl[(size_t)row * HC + col] = v;
                else if (col < 512) xr[(size_t)row * HC + (col - 256)] = v;
                else if (col < 544) proj[(size_t)row * C_CH + (col - 512)] = v;
            }
        }
    }
}

// ---------------- fused node aggregation: logits + exp + weighted sum + epilogue ----------------
__global__ __launch_bounds__(256) void node_agg_kernel(
    const int* __restrict__ offs, const int* __restrict__ csr_src,
    const int* __restrict__ csr_eid, const float* __restrict__ csr_eav,
    const float* __restrict__ We, const float* __restrict__ att,
    const float* __restrict__ xl, const float* __restrict__ xr,
    const float* __restrict__ proj, const float* __restrict__ bias,
    float* __restrict__ aexp_out, float* __restrict__ denom, float* __restrict__ xnew)
{
    const int lane = threadIdx.x & 63;
    const int d = blockIdx.x * 4 + (threadIdx.x >> 6);
    if (d >= N_NODES) return;

    const float4 we = ((const float4*)We)[lane];
    const float4 at = ((const float4*)att)[lane];
    const float4 vr = ((const float4*)(xr + (size_t)d * HC))[lane];
    const int h = lane >> 3;

    float4 acc = make_float4(0.f, 0.f, 0.f, 0.f);
    float den = 0.f;

    int i = offs[d];
    const int end = offs[d + 1];

    int s0 = 0, e0 = 0; float ea0 = 0.f; float4 vl0 = make_float4(0.f, 0.f, 0.f, 0.f);
    if (i < end) {
        s0 = csr_src[i]; e0 = csr_eid[i]; ea0 = csr_eav[i];
        vl0 = ((const float4*)(xl + (size_t)s0 * HC))[lane];
    }
    while (i < end) {
        const int j = i + 1;
        int s1 = 0, e1 = 0; float ea1 = 0.f; float4 vl1 = make_float4(0.f, 0.f, 0.f, 0.f);
        if (j < end) {
            s1 = csr_src[j]; e1 = csr_eid[j]; ea1 = csr_eav[j];
            vl1 = ((const float4*)(xl + (size_t)s1 * HC))[lane];
        }

        float m0 = vl0.x + vr.x + ea0 * we.x;
        float m1 = vl0.y + vr.y + ea0 * we.y;
        float m2 = vl0.z + vr.z + ea0 * we.z;
        float m3 = vl0.w + vr.w + ea0 * we.w;
        m0 = (m0 > 0.f) ? m0 : NEG_SLOPE * m0;
        m1 = (m1 > 0.f) ? m1 : NEG_SLOPE * m1;
        m2 = (m2 > 0.f) ? m2 : NEG_SLOPE * m2;
        m3 = (m3 > 0.f) ? m3 : NEG_SLOPE * m3;
        float tt = m0 * at.x + m1 * at.y + m2 * at.z + m3 * at.w;
        tt += __shfl_xor(tt, 1);
        tt += __shfl_xor(tt, 2);
        tt += __shfl_xor(tt, 4);
        const float aex = __expf(tt);

        if ((lane & 7) == 0) aexp_out[(size_t)e0 * H_HEADS + h] = aex;
        acc.x += aex * vl0.x; acc.y += aex * vl0.y;
        acc.z += aex * vl0.z; acc.w += aex * vl0.w;
        den += aex;

        s0 = s1; e0 = e1; ea0 = ea1; vl0 = vl1; i = j;
    }

    if ((lane & 7) == 0) denom[(size_t)d * H_HEADS + h] = den;

    const float inv = 1.f / den;
    acc.x *= inv; acc.y *= inv; acc.z *= inv; acc.w *= inv;
    #pragma unroll
    for (int mask = 8; mask <= 32; mask <<= 1) {
        acc.x += __shfl_xor(acc.x, mask);
        acc.y += __shfl_xor(acc.y, mask);
        acc.z += __shfl_xor(acc.z, mask);
        acc.w += __shfl_xor(acc.w, mask);
    }
    if (lane < 8) {
        const float4 bi = ((const float4*)bias)[lane];
        const float4 pr = ((const float4*)(proj + (size_t)d * C_CH))[lane];
        float4 r;
        r.x = fmaxf(acc.x * 0.125f + bi.x, 0.f) + pr.x;
        r.y = fmaxf(acc.y * 0.125f + bi.y, 0.f) + pr.y;
        r.z = fmaxf(acc.z * 0.125f + bi.z, 0.f) + pr.z;
        r.w = fmaxf(acc.w * 0.125f + bi.w, 0.f) + pr.w;
        ((float4*)(xnew + (size_t)d * C_CH))[lane] = r;
    }
}

// ---------------- normalized alpha write ----------------
__global__ __launch_bounds__(256) void alpha_kernel(
    const int* __restrict__ ei, const float* __restrict__ aexp,
    const float* __restrict__ denom, float* __restrict__ alpha_out)
{
    int idx = blockIdx.x * 256 + threadIdx.x;   // e*8 + h
    if (idx >= EN_TOT * H_HEADS) return;
    int e = idx >> 3, h = idx & 7;
    int d = (e < N_EDGES) ? ei[N_EDGES + e] : (e - N_EDGES);
    alpha_out[idx] = aexp[idx] / denom[(size_t)d * H_HEADS + h];
}

extern "C" void kernel_launch(void* const* d_in, const int* in_sizes, int n_in,
                              void* d_out, int out_size, void* d_ws, size_t ws_size,
                              hipStream_t stream) {
    const float* x         = (const float*)d_in[0];
    const int*   ei        = (const int*)d_in[1];
    const float* edge_attr = (const float*)d_in[2];
    // d_in[3] = batch (unused)
    const float* Wl        = (const float*)d_in[4];
    const float* Wr        = (const float*)d_in[5];
    const float* We        = (const float*)d_in[6];
    const float* att       = (const float*)d_in[7];
    const float* bias      = (const float*)d_in[8];
    const float* Wproj     = (const float*)d_in[9];

    float* ws    = (float*)d_ws;
    float* xl    = ws + OFF_XL;
    float* xr    = ws + OFF_XR;
    float* proj  = ws + OFF_PROJ;
    float* aexp  = ws + OFF_AEXP;
    float* denom = ws + OFF_DENOM;
    float* part  = ws + OFF_PART;
    float* meanp = ws + OFF_MEAN;
    float* ceav  = ws + OFF_CEAV;
    int*   csrc  = (int*)(ws + OFF_CSRC);
    int*   ceid  = (int*)(ws + OFF_CEID);
    int*   deg   = (int*)(ws + OFF_DEG);
    int*   offs  = (int*)(ws + OFF_OFFS);
    int*   cur   = (int*)(ws + OFF_CUR);

    // bf16 staging buffers aliased onto aexp/denom (written only later by node_agg)
    unsigned short* xbf  = (unsigned short*)aexp;    // 12.8 MB <= 14.4 MB
    unsigned short* wcat = (unsigned short*)denom;   // 139 KB  <= 1.6 MB

    float* out_xnew  = (float*)d_out;
    float* out_alpha = (float*)d_out + (size_t)N_NODES * C_CH;

    hipMemsetAsync(deg, 0, N_NODES * sizeof(int), stream);

    convert_kernel<<<(XCHUNKS + WCHUNKS + 255) / 256, 256, 0, stream>>>(x, Wl, Wr, Wproj, xbf, wcat);

    hist_mean_kernel<<<1024, 256, 0, stream>>>(ei, edge_attr, deg, part);
    mean_final_kernel<<<1, 256, 0, stream>>>(part, meanp);
    prefix_kernel<<<1, 1024, 0, stream>>>(deg, offs, cur);
    scatter_kernel<<<(EN_TOT + 255) / 256, 256, 0, stream>>>(ei, edge_attr, meanp, cur,
                                                             csrc, ceid, ceav);

    dim3 ggrid((N_NODES + GM - 1) / GM, (544 + GN - 1) / GN);
    gemm_mfma_kernel<<<ggrid, 256, 0, stream>>>(xbf, wcat, xl, xr, proj);

    node_agg_kernel<<<(N_NODES + 3) / 4, 256, 0, stream>>>(offs, csrc, ceid, ceav,
                                                           We, att, xl, xr, proj, bias,
                                                           aexp, denom, out_xnew);

    alpha_kernel<<<(EN_TOT * H_HEADS + 255) / 256, 256, 0, stream>>>(ei, aexp, denom, out_alpha);
}

// Round 5
// 219.386 us; speedup vs baseline: 25.9349x; 1.4547x over previous
//
#include <hip/hip_runtime.h>
#include <math.h>

#define N_NODES 50000
#define N_EDGES 400000
#define EN_TOT  450000
#define IN_DIM  128
#define H_HEADS 8
#define C_CH    32
#define HC      256
#define NEG_SLOPE 0.2f

typedef __attribute__((ext_vector_type(8))) short bf16x8;
typedef __attribute__((ext_vector_type(4))) float f32x4;

// ---------------- workspace layout ----------------
// floats
#define OFF_XL    0                                   // x_l  [N, 256]
#define OFF_XR    (OFF_XL + N_NODES * HC)             // x_r  [N, 256]
#define OFF_PROJ  (OFF_XR + N_NODES * HC)             // proj [N, 32]
#define OFF_AEXP  (OFF_PROJ + N_NODES * C_CH)         // aexp [E+N, 8]  (aliased: xbf during GEMM phase)
#define OFF_DENOM (OFF_AEXP + EN_TOT * H_HEADS)       // denom[N, 8]   (aliased: wcat during GEMM phase)
#define OFF_PART  (OFF_DENOM + N_NODES * H_HEADS)     // partial sums [1024]
#define OFF_MEAN  (OFF_PART + 1024)                   // mean scalar [1]
#define OFF_CEAV  (OFF_MEAN + 1)                      // csr_eav [E+N]
// ints (carved from float ws, 4B each)
#define OFF_CSRC  (OFF_CEAV + EN_TOT)                 // csr_src [E+N]
#define OFF_CEID  (OFF_CSRC + EN_TOT)                 // csr_eid [E+N]
#define OFF_DEG   (OFF_CEID + EN_TOT)                 // deg     [N]
#define OFF_OFFS  (OFF_DEG + N_NODES)                 // offs    [N+1]
#define OFF_CUR   (OFF_OFFS + N_NODES + 1)            // cursor  [N]
#define OFF_BSUM  (OFF_CUR + N_NODES)                 // block sums [256]

#define SCAN_B 196   // ceil(50000/256)

// ---------------- fp32 -> bf16 (RNE) ----------------
__device__ __forceinline__ unsigned f2bf(float f) {
    unsigned u = __float_as_uint(f);
    u += 0x7fffu + ((u >> 16) & 1u);
    return u >> 16;
}

// convert x [50000,128] and Wcat=[Wl;Wr;Wproj] [544,128] to bf16
#define XCHUNKS 800000            // 50000*128/8
#define WCHUNKS 8704              // 544*128/8
__global__ __launch_bounds__(256) void convert_kernel(
    const float* __restrict__ x,
    const float* __restrict__ Wl, const float* __restrict__ Wr, const float* __restrict__ Wproj,
    unsigned short* __restrict__ xbf, unsigned short* __restrict__ wcat)
{
    int t = blockIdx.x * 256 + threadIdx.x;
    const float* src; uint4* dst;
    if (t < XCHUNKS) {
        src = x + (size_t)t * 8;
        dst = (uint4*)xbf + t;
    } else if (t < XCHUNKS + WCHUNKS) {
        int c = t - XCHUNKS;
        int j = (c * 8) >> 7, k = (c * 8) & 127;
        src = (j < 256 ? Wl + (size_t)j * 128 : (j < 512 ? Wr + (size_t)(j - 256) * 128
                                                         : Wproj + (size_t)(j - 512) * 128)) + k;
        dst = (uint4*)wcat + c;
    } else return;
    float4 a = ((const float4*)src)[0];
    float4 b = ((const float4*)src)[1];
    uint4 o;
    o.x = f2bf(a.x) | (f2bf(a.y) << 16);
    o.y = f2bf(a.z) | (f2bf(a.w) << 16);
    o.z = f2bf(b.x) | (f2bf(b.y) << 16);
    o.w = f2bf(b.z) | (f2bf(b.w) << 16);
    *dst = o;
}

// ---------------- fused hist (over dst) + edge_attr partial sums ----------------
__global__ __launch_bounds__(256) void hist_mean_kernel(
    const int* __restrict__ ei, const float* __restrict__ ea,
    int* __restrict__ deg, float* __restrict__ part)
{
    __shared__ float sd[256];
    int t = threadIdx.x;
    int g = blockIdx.x * 256 + t;
    float s = 0.f;
    for (int i = g; i < N_EDGES; i += 1024 * 256) s += ea[i];
    for (int i = g; i < EN_TOT; i += 1024 * 256) {
        int d = (i < N_EDGES) ? ei[N_EDGES + i] : (i - N_EDGES);
        atomicAdd(&deg[d], 1);
    }
    sd[t] = s; __syncthreads();
    for (int w = 128; w > 0; w >>= 1) { if (t < w) sd[t] += sd[t + w]; __syncthreads(); }
    if (t == 0) part[blockIdx.x] = sd[0];
}

__global__ void mean_final_kernel(const float* __restrict__ part, float* __restrict__ mean_out) {
    __shared__ float sd[256];
    int t = threadIdx.x;
    float s = part[t] + part[t + 256] + part[t + 512] + part[t + 768];
    sd[t] = s; __syncthreads();
    for (int w = 128; w > 0; w >>= 1) { if (t < w) sd[t] += sd[t + w]; __syncthreads(); }
    if (t == 0) mean_out[0] = sd[0] / (float)N_EDGES;
}

// ---------------- parallel 3-phase exclusive scan of deg[50000] ----------------
__global__ __launch_bounds__(256) void scan_part_kernel(const int* __restrict__ deg,
                                                        int* __restrict__ bsum) {
    __shared__ int sd[256];
    int t = threadIdx.x;
    int i = blockIdx.x * 256 + t;
    int v = (i < N_NODES) ? deg[i] : 0;
    sd[t] = v; __syncthreads();
    for (int w = 128; w > 0; w >>= 1) { if (t < w) sd[t] += sd[t + w]; __syncthreads(); }
    if (t == 0) bsum[blockIdx.x] = sd[0];
}

__global__ __launch_bounds__(256) void scan_mid_kernel(int* __restrict__ bsum) {
    __shared__ int sd[256];
    int t = threadIdx.x;
    int v = (t < SCAN_B) ? bsum[t] : 0;
    sd[t] = v; __syncthreads();
    #pragma unroll
    for (int ofs = 1; ofs < 256; ofs <<= 1) {
        int u = (t >= ofs) ? sd[t - ofs] : 0;
        __syncthreads();
        sd[t] += u;
        __syncthreads();
    }
    if (t < SCAN_B) bsum[t] = sd[t] - v;   // exclusive
}

__global__ __launch_bounds__(256) void scan_final_kernel(
    const int* __restrict__ deg, const int* __restrict__ bsum,
    int* __restrict__ offs, int* __restrict__ cur) {
    __shared__ int sd[256];
    int t = threadIdx.x;
    int i = blockIdx.x * 256 + t;
    int v = (i < N_NODES) ? deg[i] : 0;
    sd[t] = v; __syncthreads();
    #pragma unroll
    for (int ofs = 1; ofs < 256; ofs <<= 1) {
        int u = (t >= ofs) ? sd[t - ofs] : 0;
        __syncthreads();
        sd[t] += u;
        __syncthreads();
    }
    int excl = bsum[blockIdx.x] + sd[t] - v;
    if (i < N_NODES) { offs[i] = excl; cur[i] = excl; }
    if (i == N_NODES - 1) offs[N_NODES] = excl + v;
}

__global__ __launch_bounds__(256) void scatter_kernel(
    const int* __restrict__ ei, const float* __restrict__ edge_attr,
    const float* __restrict__ mean_attr, int* __restrict__ cur,
    int* __restrict__ csr_src, int* __restrict__ csr_eid, float* __restrict__ csr_eav)
{
    int e = blockIdx.x * 256 + threadIdx.x;
    if (e >= EN_TOT) return;
    int s, d; float eav;
    if (e < N_EDGES) { s = ei[e]; d = ei[N_EDGES + e]; eav = edge_attr[e]; }
    else { s = e - N_EDGES; d = s; eav = mean_attr[0]; }
    int pos = atomicAdd(&cur[d], 1);
    csr_src[pos] = s;
    csr_eid[pos] = e;
    csr_eav[pos] = eav;
}

// ---------------- MFMA GEMM: [x_l | x_r | proj] = x @ Wcat^T (bf16 in, fp32 out) ----------------
#define GM 128
#define GN 64

__global__ __launch_bounds__(256) void gemm_mfma_kernel(
    const unsigned short* __restrict__ xbf, const unsigned short* __restrict__ wcat,
    float* __restrict__ xl, float* __restrict__ xr, float* __restrict__ proj)
{
    __shared__ unsigned short As[GM * 128];   // 32 KB
    __shared__ unsigned short Bs[GN * 128];   // 16 KB
    const int t = threadIdx.x;
    const int m0 = blockIdx.x * GM;
    const int n0 = blockIdx.y * GN;

    #pragma unroll
    for (int cc = 0; cc < 8; ++cc) {
        int c = t + cc * 256;
        int r = c >> 4;
        int k0 = (c & 15) * 8;
        int row = m0 + r;
        uint4 v = make_uint4(0, 0, 0, 0);
        if (row < N_NODES) v = *((const uint4*)(xbf + (size_t)row * 128 + k0));
        int byte = (r * 256 + k0 * 2) ^ ((r & 7) << 4);
        *((uint4*)((char*)As + byte)) = v;
    }
    #pragma unroll
    for (int cc = 0; cc < 4; ++cc) {
        int c = t + cc * 256;
        int r = c >> 4;
        int k0 = (c & 15) * 8;
        int j = n0 + r;
        uint4 v = make_uint4(0, 0, 0, 0);
        if (j < 544) v = *((const uint4*)(wcat + (size_t)j * 128 + k0));
        int byte = (r * 256 + k0 * 2) ^ ((r & 7) << 4);
        *((uint4*)((char*)Bs + byte)) = v;
    }
    __syncthreads();

    const int wid = t >> 6, lane = t & 63;
    const int wr = wid >> 1, wc = wid & 1;
    const int lrow = lane & 15;
    const int kgrp = (lane >> 4) * 8;

    f32x4 acc[4][2] = {};
    #pragma unroll
    for (int kk = 0; kk < 4; ++kk) {
        bf16x8 a[4], b[2];
        #pragma unroll
        for (int fm = 0; fm < 4; ++fm) {
            int r = wr * 64 + fm * 16 + lrow;
            int byte = (r * 256 + (kk * 32 + kgrp) * 2) ^ ((r & 7) << 4);
            a[fm] = *((const bf16x8*)((const char*)As + byte));
        }
        #pragma unroll
        for (int fn = 0; fn < 2; ++fn) {
            int r = wc * 32 + fn * 16 + lrow;
            int byte = (r * 256 + (kk * 32 + kgrp) * 2) ^ ((r & 7) << 4);
            b[fn] = *((const bf16x8*)((const char*)Bs + byte));
        }
        #pragma unroll
        for (int fm = 0; fm < 4; ++fm)
            #pragma unroll
            for (int fn = 0; fn < 2; ++fn)
                acc[fm][fn] = __builtin_amdgcn_mfma_f32_16x16x32_bf16(a[fm], b[fn], acc[fm][fn], 0, 0, 0);
    }

    const int crow0 = (lane >> 4) * 4;
    const int ccol = lane & 15;
    #pragma unroll
    for (int fm = 0; fm < 4; ++fm) {
        #pragma unroll
        for (int fn = 0; fn < 2; ++fn) {
            #pragma unroll
            for (int r = 0; r < 4; ++r) {
                int row = m0 + wr * 64 + fm * 16 + crow0 + r;
                int col = n0 + wc * 32 + fn * 16 + ccol;
                if (row >= N_NODES) continue;
                float v = acc[fm][fn][r];
                if (col < 256)      xl[(size_t)row * HC + col] = v;
                else if (col < 512) xr[(size_t)row * HC + (col - 256)] = v;
                else if (col < 544) proj[(size_t)row * C_CH + (col - 512)] = v;
            }
        }
    }
}

// ---------------- fused node aggregation: logits + exp + weighted sum + epilogue ----------------
__global__ __launch_bounds__(256) void node_agg_kernel(
    const int* __restrict__ offs, const int* __restrict__ csr_src,
    const int* __restrict__ csr_eid, const float* __restrict__ csr_eav,
    const float* __restrict__ We, const float* __restrict__ att,
    const float* __restrict__ xl, const float* __restrict__ xr,
    const float* __restrict__ proj, const float* __restrict__ bias,
    float* __restrict__ aexp_out, float* __restrict__ denom, float* __restrict__ xnew)
{
    const int lane = threadIdx.x & 63;
    const int d = blockIdx.x * 4 + (threadIdx.x >> 6);
    if (d >= N_NODES) return;

    const float4 we = ((const float4*)We)[lane];
    const float4 at = ((const float4*)att)[lane];
    const float4 vr = ((const float4*)(xr + (size_t)d * HC))[lane];
    const int h = lane >> 3;

    float4 acc = make_float4(0.f, 0.f, 0.f, 0.f);
    float den = 0.f;

    int i = offs[d];
    const int end = offs[d + 1];

    int s0 = 0, e0 = 0; float ea0 = 0.f; float4 vl0 = make_float4(0.f, 0.f, 0.f, 0.f);
    if (i < end) {
        s0 = csr_src[i]; e0 = csr_eid[i]; ea0 = csr_eav[i];
        vl0 = ((const float4*)(xl + (size_t)s0 * HC))[lane];
    }
    while (i < end) {
        const int j = i + 1;
        int s1 = 0, e1 = 0; float ea1 = 0.f; float4 vl1 = make_float4(0.f, 0.f, 0.f, 0.f);
        if (j < end) {
            s1 = csr_src[j]; e1 = csr_eid[j]; ea1 = csr_eav[j];
            vl1 = ((const float4*)(xl + (size_t)s1 * HC))[lane];
        }

        float m0 = vl0.x + vr.x + ea0 * we.x;
        float m1 = vl0.y + vr.y + ea0 * we.y;
        float m2 = vl0.z + vr.z + ea0 * we.z;
        float m3 = vl0.w + vr.w + ea0 * we.w;
        m0 = (m0 > 0.f) ? m0 : NEG_SLOPE * m0;
        m1 = (m1 > 0.f) ? m1 : NEG_SLOPE * m1;
        m2 = (m2 > 0.f) ? m2 : NEG_SLOPE * m2;
        m3 = (m3 > 0.f) ? m3 : NEG_SLOPE * m3;
        float tt = m0 * at.x + m1 * at.y + m2 * at.z + m3 * at.w;
        tt += __shfl_xor(tt, 1);
        tt += __shfl_xor(tt, 2);
        tt += __shfl_xor(tt, 4);
        const float aex = __expf(tt);

        if ((lane & 7) == 0) aexp_out[(size_t)e0 * H_HEADS + h] = aex;
        acc.x += aex * vl0.x; acc.y += aex * vl0.y;
        acc.z += aex * vl0.z; acc.w += aex * vl0.w;
        den += aex;

        s0 = s1; e0 = e1; ea0 = ea1; vl0 = vl1; i = j;
    }

    if ((lane & 7) == 0) denom[(size_t)d * H_HEADS + h] = den;

    const float inv = 1.f / den;
    acc.x *= inv; acc.y *= inv; acc.z *= inv; acc.w *= inv;
    #pragma unroll
    for (int mask = 8; mask <= 32; mask <<= 1) {
        acc.x += __shfl_xor(acc.x, mask);
        acc.y += __shfl_xor(acc.y, mask);
        acc.z += __shfl_xor(acc.z, mask);
        acc.w += __shfl_xor(acc.w, mask);
    }
    if (lane < 8) {
        const float4 bi = ((const float4*)bias)[lane];
        const float4 pr = ((const float4*)(proj + (size_t)d * C_CH))[lane];
        float4 r;
        r.x = fmaxf(acc.x * 0.125f + bi.x, 0.f) + pr.x;
        r.y = fmaxf(acc.y * 0.125f + bi.y, 0.f) + pr.y;
        r.z = fmaxf(acc.z * 0.125f + bi.z, 0.f) + pr.z;
        r.w = fmaxf(acc.w * 0.125f + bi.w, 0.f) + pr.w;
        ((float4*)(xnew + (size_t)d * C_CH))[lane] = r;
    }
}

// ---------------- normalized alpha write ----------------
__global__ __launch_bounds__(256) void alpha_kernel(
    const int* __restrict__ ei, const float* __restrict__ aexp,
    const float* __restrict__ denom, float* __restrict__ alpha_out)
{
    int idx = blockIdx.x * 256 + threadIdx.x;   // e*8 + h
    if (idx >= EN_TOT * H_HEADS) return;
    int e = idx >> 3, h = idx & 7;
    int d = (e < N_EDGES) ? ei[N_EDGES + e] : (e - N_EDGES);
    alpha_out[idx] = aexp[idx] / denom[(size_t)d * H_HEADS + h];
}

extern "C" void kernel_launch(void* const* d_in, const int* in_sizes, int n_in,
                              void* d_out, int out_size, void* d_ws, size_t ws_size,
                              hipStream_t stream) {
    const float* x         = (const float*)d_in[0];
    const int*   ei        = (const int*)d_in[1];
    const float* edge_attr = (const float*)d_in[2];
    // d_in[3] = batch (unused)
    const float* Wl        = (const float*)d_in[4];
    const float* Wr        = (const float*)d_in[5];
    const float* We        = (const float*)d_in[6];
    const float* att       = (const float*)d_in[7];
    const float* bias      = (const float*)d_in[8];
    const float* Wproj     = (const float*)d_in[9];

    float* ws    = (float*)d_ws;
    float* xl    = ws + OFF_XL;
    float* xr    = ws + OFF_XR;
    float* proj  = ws + OFF_PROJ;
    float* aexp  = ws + OFF_AEXP;
    float* denom = ws + OFF_DENOM;
    float* part  = ws + OFF_PART;
    float* meanp = ws + OFF_MEAN;
    float* ceav  = ws + OFF_CEAV;
    int*   csrc  = (int*)(ws + OFF_CSRC);
    int*   ceid  = (int*)(ws + OFF_CEID);
    int*   deg   = (int*)(ws + OFF_DEG);
    int*   offs  = (int*)(ws + OFF_OFFS);
    int*   cur   = (int*)(ws + OFF_CUR);
    int*   bsum  = (int*)(ws + OFF_BSUM);

    // bf16 staging buffers aliased onto aexp/denom (written only later by node_agg)
    unsigned short* xbf  = (unsigned short*)aexp;    // 12.8 MB <= 14.4 MB
    unsigned short* wcat = (unsigned short*)denom;   // 139 KB  <= 1.6 MB

    float* out_xnew  = (float*)d_out;
    float* out_alpha = (float*)d_out + (size_t)N_NODES * C_CH;

    hipMemsetAsync(deg, 0, N_NODES * sizeof(int), stream);

    convert_kernel<<<(XCHUNKS + WCHUNKS + 255) / 256, 256, 0, stream>>>(x, Wl, Wr, Wproj, xbf, wcat);

    hist_mean_kernel<<<1024, 256, 0, stream>>>(ei, edge_attr, deg, part);
    mean_final_kernel<<<1, 256, 0, stream>>>(part, meanp);

    scan_part_kernel<<<SCAN_B, 256, 0, stream>>>(deg, bsum);
    scan_mid_kernel<<<1, 256, 0, stream>>>(bsum);
    scan_final_kernel<<<SCAN_B, 256, 0, stream>>>(deg, bsum, offs, cur);

    scatter_kernel<<<(EN_TOT + 255) / 256, 256, 0, stream>>>(ei, edge_attr, meanp, cur,
                                                             csrc, ceid, ceav);

    dim3 ggrid((N_NODES + GM - 1) / GM, (544 + GN - 1) / GN);
    gemm_mfma_kernel<<<ggrid, 256, 0, stream>>>(xbf, wcat, xl, xr, proj);

    node_agg_kernel<<<(N_NODES + 3) / 4, 256, 0, stream>>>(offs, csrc, ceid, ceav,
                                                           We, att, xl, xr, proj, bias,
                                                           aexp, denom, out_xnew);

    alpha_kernel<<<(EN_TOT * H_HEADS + 255) / 256, 256, 0, stream>>>(ei, aexp, denom, out_alpha);
}

// Round 7
// 204.039 us; speedup vs baseline: 27.8857x; 1.0752x over previous
//
#include <hip/hip_runtime.h>
#include <math.h>

#define N_NODES 50000
#define N_EDGES 400000
#define EN_TOT  450000
#define IN_DIM  128
#define H_HEADS 8
#define C_CH    32
#define HC      256
#define NEG_SLOPE 0.2f

typedef __attribute__((ext_vector_type(8))) short bf16x8;
typedef __attribute__((ext_vector_type(4))) float f32x4;

// ---------------- workspace layout (float slots; no aliasing) ----------------
// UNIT DISCIPLINE: every region's size below is in FLOAT slots. bf16 regions
// hold 2 shorts per float slot. (Round-6 failure: wcat reserved in SHORT count
// by mistake -> convert clobbered part/ceav -> NaN weights.)
#define OFF_XLB   0                                   // x_l bf16 [N,256]: N*HC shorts = N*HC/2 floats
#define OFF_XRB   (OFF_XLB + N_NODES * HC / 2)        // x_r bf16 [N,256]
#define OFF_PROJ  (OFF_XRB + N_NODES * HC / 2)        // proj fp32 [N,32]
#define OFF_AEXP  (OFF_PROJ + N_NODES * C_CH)         // aexp [E+N,8] fp32
#define OFF_DENOM (OFF_AEXP + EN_TOT * H_HEADS)       // denom [N,8] fp32
#define OFF_XBF   (OFF_DENOM + N_NODES * H_HEADS)     // x bf16 [N,128]: N*128 shorts = N*64 floats
#define OFF_WCAT  (OFF_XBF + N_NODES * 64)            // Wcat bf16 [544,128]: 69632 shorts = 34816 floats
#define OFF_PART  (OFF_WCAT + 34816)                  // partial sums [1024]
#define OFF_MEAN  (OFF_PART + 1024)
#define OFF_CEAV  (OFF_MEAN + 1)                      // csr_eav [E+N]
#define OFF_CSRC  (OFF_CEAV + EN_TOT)                 // csr_src [E+N]
#define OFF_CEID  (OFF_CSRC + EN_TOT)                 // csr_eid [E+N]
#define OFF_DEG   (OFF_CEID + EN_TOT)                 // deg  [N]
#define OFF_OFFS  (OFF_DEG + N_NODES)                 // offs [N+1]
#define OFF_CUR   (OFF_OFFS + N_NODES + 1)            // cursor [N]
#define OFF_BSUM  (OFF_CUR + N_NODES)                 // block sums [256]

#define SCAN_B 196   // ceil(50000/256)

// ---------------- fp32 -> bf16 (RNE) ----------------
__device__ __forceinline__ unsigned f2bf(float f) {
    unsigned u = __float_as_uint(f);
    u += 0x7fffu + ((u >> 16) & 1u);
    return u >> 16;
}
__device__ __forceinline__ float bflo(unsigned u) { return __uint_as_float(u << 16); }
__device__ __forceinline__ float bfhi(unsigned u) { return __uint_as_float(u & 0xffff0000u); }

// convert x [50000,128] and Wcat=[Wl;Wr;Wproj] [544,128] to bf16
#define XCHUNKS 800000            // 50000*128/8
#define WCHUNKS 8704              // 544*128/8
__global__ __launch_bounds__(256) void convert_kernel(
    const float* __restrict__ x,
    const float* __restrict__ Wl, const float* __restrict__ Wr, const float* __restrict__ Wproj,
    unsigned short* __restrict__ xbf, unsigned short* __restrict__ wcat)
{
    int t = blockIdx.x * 256 + threadIdx.x;
    const float* src; uint4* dst;
    if (t < XCHUNKS) {
        src = x + (size_t)t * 8;
        dst = (uint4*)xbf + t;
    } else if (t < XCHUNKS + WCHUNKS) {
        int c = t - XCHUNKS;
        int j = (c * 8) >> 7, k = (c * 8) & 127;
        src = (j < 256 ? Wl + (size_t)j * 128 : (j < 512 ? Wr + (size_t)(j - 256) * 128
                                                         : Wproj + (size_t)(j - 512) * 128)) + k;
        dst = (uint4*)wcat + c;
    } else return;
    float4 a = ((const float4*)src)[0];
    float4 b = ((const float4*)src)[1];
    uint4 o;
    o.x = f2bf(a.x) | (f2bf(a.y) << 16);
    o.y = f2bf(a.z) | (f2bf(a.w) << 16);
    o.z = f2bf(b.x) | (f2bf(b.y) << 16);
    o.w = f2bf(b.z) | (f2bf(b.w) << 16);
    *dst = o;
}

// ---------------- fused hist (over dst) + edge_attr partial sums ----------------
__global__ __launch_bounds__(256) void hist_mean_kernel(
    const int* __restrict__ ei, const float* __restrict__ ea,
    int* __restrict__ deg, float* __restrict__ part)
{
    __shared__ float sd[256];
    int t = threadIdx.x;
    int g = blockIdx.x * 256 + t;
    float s = 0.f;
    for (int i = g; i < N_EDGES; i += 1024 * 256) s += ea[i];
    for (int i = g; i < EN_TOT; i += 1024 * 256) {
        int d = (i < N_EDGES) ? ei[N_EDGES + i] : (i - N_EDGES);
        atomicAdd(&deg[d], 1);
    }
    sd[t] = s; __syncthreads();
    for (int w = 128; w > 0; w >>= 1) { if (t < w) sd[t] += sd[t + w]; __syncthreads(); }
    if (t == 0) part[blockIdx.x] = sd[0];
}

__global__ void mean_final_kernel(const float* __restrict__ part, float* __restrict__ mean_out) {
    __shared__ float sd[256];
    int t = threadIdx.x;
    float s = part[t] + part[t + 256] + part[t + 512] + part[t + 768];
    sd[t] = s; __syncthreads();
    for (int w = 128; w > 0; w >>= 1) { if (t < w) sd[t] += sd[t + w]; __syncthreads(); }
    if (t == 0) mean_out[0] = sd[0] / (float)N_EDGES;
}

// ---------------- parallel 3-phase exclusive scan of deg[50000] ----------------
__global__ __launch_bounds__(256) void scan_part_kernel(const int* __restrict__ deg,
                                                        int* __restrict__ bsum) {
    __shared__ int sd[256];
    int t = threadIdx.x;
    int i = blockIdx.x * 256 + t;
    int v = (i < N_NODES) ? deg[i] : 0;
    sd[t] = v; __syncthreads();
    for (int w = 128; w > 0; w >>= 1) { if (t < w) sd[t] += sd[t + w]; __syncthreads(); }
    if (t == 0) bsum[blockIdx.x] = sd[0];
}

__global__ __launch_bounds__(256) void scan_mid_kernel(int* __restrict__ bsum) {
    __shared__ int sd[256];
    int t = threadIdx.x;
    int v = (t < SCAN_B) ? bsum[t] : 0;
    sd[t] = v; __syncthreads();
    #pragma unroll
    for (int ofs = 1; ofs < 256; ofs <<= 1) {
        int u = (t >= ofs) ? sd[t - ofs] : 0;
        __syncthreads();
        sd[t] += u;
        __syncthreads();
    }
    if (t < SCAN_B) bsum[t] = sd[t] - v;   // exclusive
}

__global__ __launch_bounds__(256) void scan_final_kernel(
    const int* __restrict__ deg, const int* __restrict__ bsum,
    int* __restrict__ offs, int* __restrict__ cur) {
    __shared__ int sd[256];
    int t = threadIdx.x;
    int i = blockIdx.x * 256 + t;
    int v = (i < N_NODES) ? deg[i] : 0;
    sd[t] = v; __syncthreads();
    #pragma unroll
    for (int ofs = 1; ofs < 256; ofs <<= 1) {
        int u = (t >= ofs) ? sd[t - ofs] : 0;
        __syncthreads();
        sd[t] += u;
        __syncthreads();
    }
    int excl = bsum[blockIdx.x] + sd[t] - v;
    if (i < N_NODES) { offs[i] = excl; cur[i] = excl; }
    if (i == N_NODES - 1) offs[N_NODES] = excl + v;
}

__global__ __launch_bounds__(256) void scatter_kernel(
    const int* __restrict__ ei, const float* __restrict__ edge_attr,
    const float* __restrict__ mean_attr, int* __restrict__ cur,
    int* __restrict__ csr_src, int* __restrict__ csr_eid, float* __restrict__ csr_eav)
{
    int e = blockIdx.x * 256 + threadIdx.x;
    if (e >= EN_TOT) return;
    int s, d; float eav;
    if (e < N_EDGES) { s = ei[e]; d = ei[N_EDGES + e]; eav = edge_attr[e]; }
    else { s = e - N_EDGES; d = s; eav = mean_attr[0]; }
    int pos = atomicAdd(&cur[d], 1);
    csr_src[pos] = s;
    csr_eid[pos] = e;
    csr_eav[pos] = eav;
}

// ---------------- MFMA GEMM: bf16 in, bf16 out for xl/xr, fp32 for proj ----------------
#define GM 128
#define GN 64

__global__ __launch_bounds__(256) void gemm_mfma_kernel(
    const unsigned short* __restrict__ xbf, const unsigned short* __restrict__ wcat,
    unsigned short* __restrict__ xlb, unsigned short* __restrict__ xrb,
    float* __restrict__ proj)
{
    __shared__ unsigned short As[GM * 128];   // 32 KB
    __shared__ unsigned short Bs[GN * 128];   // 16 KB
    const int t = threadIdx.x;
    const int m0 = blockIdx.x * GM;
    const int n0 = blockIdx.y * GN;

    #pragma unroll
    for (int cc = 0; cc < 8; ++cc) {
        int c = t + cc * 256;
        int r = c >> 4;
        int k0 = (c & 15) * 8;
        int row = m0 + r;
        uint4 v = make_uint4(0, 0, 0, 0);
        if (row < N_NODES) v = *((const uint4*)(xbf + (size_t)row * 128 + k0));
        int byte = (r * 256 + k0 * 2) ^ ((r & 7) << 4);
        *((uint4*)((char*)As + byte)) = v;
    }
    #pragma unroll
    for (int cc = 0; cc < 4; ++cc) {
        int c = t + cc * 256;
        int r = c >> 4;
        int k0 = (c & 15) * 8;
        int j = n0 + r;
        uint4 v = make_uint4(0, 0, 0, 0);
        if (j < 544) v = *((const uint4*)(wcat + (size_t)j * 128 + k0));
        int byte = (r * 256 + k0 * 2) ^ ((r & 7) << 4);
        *((uint4*)((char*)Bs + byte)) = v;
    }
    __syncthreads();

    const int wid = t >> 6, lane = t & 63;
    const int wr = wid >> 1, wc = wid & 1;
    const int lrow = lane & 15;
    const int kgrp = (lane >> 4) * 8;

    f32x4 acc[4][2] = {};
    #pragma unroll
    for (int kk = 0; kk < 4; ++kk) {
        bf16x8 a[4], b[2];
        #pragma unroll
        for (int fm = 0; fm < 4; ++fm) {
            int r = wr * 64 + fm * 16 + lrow;
            int byte = (r * 256 + (kk * 32 + kgrp) * 2) ^ ((r & 7) << 4);
            a[fm] = *((const bf16x8*)((const char*)As + byte));
        }
        #pragma unroll
        for (int fn = 0; fn < 2; ++fn) {
            int r = wc * 32 + fn * 16 + lrow;
            int byte = (r * 256 + (kk * 32 + kgrp) * 2) ^ ((r & 7) << 4);
            b[fn] = *((const bf16x8*)((const char*)Bs + byte));
        }
        #pragma unroll
        for (int fm = 0; fm < 4; ++fm)
            #pragma unroll
            for (int fn = 0; fn < 2; ++fn)
                acc[fm][fn] = __builtin_amdgcn_mfma_f32_16x16x32_bf16(a[fm], b[fn], acc[fm][fn], 0, 0, 0);
    }

    // C layout: row = (lane>>4)*4 + reg, col = lane&15  (m89-verified)
    const int crow0 = (lane >> 4) * 4;
    const int ccol = lane & 15;
    #pragma unroll
    for (int fm = 0; fm < 4; ++fm) {
        #pragma unroll
        for (int fn = 0; fn < 2; ++fn) {
            #pragma unroll
            for (int r = 0; r < 4; ++r) {
                int row = m0 + wr * 64 + fm * 16 + crow0 + r;
                int col = n0 + wc * 32 + fn * 16 + ccol;
                if (row >= N_NODES) continue;
                float v = acc[fm][fn][r];
                if (col < 256)      xlb[(size_t)row * HC + col] = (unsigned short)f2bf(v);
                else if (col < 512) xrb[(size_t)row * HC + (col - 256)] = (unsigned short)f2bf(v);
                else if (col < 544) proj[(size_t)row * C_CH + (col - 512)] = v;
            }
        }
    }
}

// ---------------- fused node aggregation (bf16 gathers) ----------------
__global__ __launch_bounds__(256) void node_agg_kernel(
    const int* __restrict__ offs, const int* __restrict__ csr_src,
    const int* __restrict__ csr_eid, const float* __restrict__ csr_eav,
    const float* __restrict__ We, const float* __restrict__ att,
    const unsigned short* __restrict__ xlb, const unsigned short* __restrict__ xrb,
    const float* __restrict__ proj, const float* __restrict__ bias,
    float* __restrict__ aexp_out, float* __restrict__ denom, float* __restrict__ xnew)
{
    const int lane = threadIdx.x & 63;
    const int d = blockIdx.x * 4 + (threadIdx.x >> 6);
    if (d >= N_NODES) return;

    const float4 we = ((const float4*)We)[lane];
    const float4 at = ((const float4*)att)[lane];
    const uint2 vru = ((const uint2*)(xrb + (size_t)d * HC))[lane];
    const float vr0 = bflo(vru.x), vr1 = bfhi(vru.x), vr2 = bflo(vru.y), vr3 = bfhi(vru.y);
    const int h = lane >> 3;

    float4 acc = make_float4(0.f, 0.f, 0.f, 0.f);
    float den = 0.f;

    int i = offs[d];
    const int end = offs[d + 1];

    int e0 = 0; float ea0 = 0.f; uint2 vl0 = make_uint2(0, 0);
    if (i < end) {
        int s0 = csr_src[i]; e0 = csr_eid[i]; ea0 = csr_eav[i];
        vl0 = ((const uint2*)(xlb + (size_t)s0 * HC))[lane];
    }
    while (i < end) {
        const int j = i + 1;
        int e1 = 0; float ea1 = 0.f; uint2 vl1 = make_uint2(0, 0);
        if (j < end) {
            int s1 = csr_src[j]; e1 = csr_eid[j]; ea1 = csr_eav[j];
            vl1 = ((const uint2*)(xlb + (size_t)s1 * HC))[lane];
        }

        const float x0 = bflo(vl0.x), x1 = bfhi(vl0.x), x2 = bflo(vl0.y), x3 = bfhi(vl0.y);
        float m0 = x0 + vr0 + ea0 * we.x;
        float m1 = x1 + vr1 + ea0 * we.y;
        float m2 = x2 + vr2 + ea0 * we.z;
        float m3 = x3 + vr3 + ea0 * we.w;
        m0 = (m0 > 0.f) ? m0 : NEG_SLOPE * m0;
        m1 = (m1 > 0.f) ? m1 : NEG_SLOPE * m1;
        m2 = (m2 > 0.f) ? m2 : NEG_SLOPE * m2;
        m3 = (m3 > 0.f) ? m3 : NEG_SLOPE * m3;
        float tt = m0 * at.x + m1 * at.y + m2 * at.z + m3 * at.w;
        tt += __shfl_xor(tt, 1);
        tt += __shfl_xor(tt, 2);
        tt += __shfl_xor(tt, 4);
        const float aex = __expf(tt);

        if ((lane & 7) == 0) aexp_out[(size_t)e0 * H_HEADS + h] = aex;
        acc.x += aex * x0; acc.y += aex * x1;
        acc.z += aex * x2; acc.w += aex * x3;
        den += aex;

        e0 = e1; ea0 = ea1; vl0 = vl1; i = j;
    }

    if ((lane & 7) == 0) denom[(size_t)d * H_HEADS + h] = den;

    const float inv = 1.f / den;
    acc.x *= inv; acc.y *= inv; acc.z *= inv; acc.w *= inv;
    #pragma unroll
    for (int mask = 8; mask <= 32; mask <<= 1) {
        acc.x += __shfl_xor(acc.x, mask);
        acc.y += __shfl_xor(acc.y, mask);
        acc.z += __shfl_xor(acc.z, mask);
        acc.w += __shfl_xor(acc.w, mask);
    }
    if (lane < 8) {
        const float4 bi = ((const float4*)bias)[lane];
        const float4 pr = ((const float4*)(proj + (size_t)d * C_CH))[lane];
        float4 r;
        r.x = fmaxf(acc.x * 0.125f + bi.x, 0.f) + pr.x;
        r.y = fmaxf(acc.y * 0.125f + bi.y, 0.f) + pr.y;
        r.z = fmaxf(acc.z * 0.125f + bi.z, 0.f) + pr.z;
        r.w = fmaxf(acc.w * 0.125f + bi.w, 0.f) + pr.w;
        ((float4*)(xnew + (size_t)d * C_CH))[lane] = r;
    }
}

// ---------------- normalized alpha write ----------------
__global__ __launch_bounds__(256) void alpha_kernel(
    const int* __restrict__ ei, const float* __restrict__ aexp,
    const float* __restrict__ denom, float* __restrict__ alpha_out)
{
    int idx = blockIdx.x * 256 + threadIdx.x;   // e*8 + h
    if (idx >= EN_TOT * H_HEADS) return;
    int e = idx >> 3, h = idx & 7;
    int d = (e < N_EDGES) ? ei[N_EDGES + e] : (e - N_EDGES);
    alpha_out[idx] = aexp[idx] / denom[(size_t)d * H_HEADS + h];
}

extern "C" void kernel_launch(void* const* d_in, const int* in_sizes, int n_in,
                              void* d_out, int out_size, void* d_ws, size_t ws_size,
                              hipStream_t stream) {
    const float* x         = (const float*)d_in[0];
    const int*   ei        = (const int*)d_in[1];
    const float* edge_attr = (const float*)d_in[2];
    // d_in[3] = batch (unused)
    const float* Wl        = (const float*)d_in[4];
    const float* Wr        = (const float*)d_in[5];
    const float* We        = (const float*)d_in[6];
    const float* att       = (const float*)d_in[7];
    const float* bias      = (const float*)d_in[8];
    const float* Wproj     = (const float*)d_in[9];

    float* ws    = (float*)d_ws;
    unsigned short* xlb  = (unsigned short*)(ws + OFF_XLB);
    unsigned short* xrb  = (unsigned short*)(ws + OFF_XRB);
    float* proj  = ws + OFF_PROJ;
    float* aexp  = ws + OFF_AEXP;
    float* denom = ws + OFF_DENOM;
    unsigned short* xbf  = (unsigned short*)(ws + OFF_XBF);
    unsigned short* wcat = (unsigned short*)(ws + OFF_WCAT);
    float* part  = ws + OFF_PART;
    float* meanp = ws + OFF_MEAN;
    float* ceav  = ws + OFF_CEAV;
    int*   csrc  = (int*)(ws + OFF_CSRC);
    int*   ceid  = (int*)(ws + OFF_CEID);
    int*   deg   = (int*)(ws + OFF_DEG);
    int*   offs  = (int*)(ws + OFF_OFFS);
    int*   cur   = (int*)(ws + OFF_CUR);
    int*   bsum  = (int*)(ws + OFF_BSUM);

    float* out_xnew  = (float*)d_out;
    float* out_alpha = (float*)d_out + (size_t)N_NODES * C_CH;

    hipMemsetAsync(deg, 0, N_NODES * sizeof(int), stream);

    convert_kernel<<<(XCHUNKS + WCHUNKS + 255) / 256, 256, 0, stream>>>(x, Wl, Wr, Wproj, xbf, wcat);

    hist_mean_kernel<<<1024, 256, 0, stream>>>(ei, edge_attr, deg, part);
    mean_final_kernel<<<1, 256, 0, stream>>>(part, meanp);

    scan_part_kernel<<<SCAN_B, 256, 0, stream>>>(deg, bsum);
    scan_mid_kernel<<<1, 256, 0, stream>>>(bsum);
    scan_final_kernel<<<SCAN_B, 256, 0, stream>>>(deg, bsum, offs, cur);

    scatter_kernel<<<(EN_TOT + 255) / 256, 256, 0, stream>>>(ei, edge_attr, meanp, cur,
                                                             csrc, ceid, ceav);

    dim3 ggrid((N_NODES + GM - 1) / GM, (544 + GN - 1) / GN);
    gemm_mfma_kernel<<<ggrid, 256, 0, stream>>>(xbf, wcat, xlb, xrb, proj);

    node_agg_kernel<<<(N_NODES + 3) / 4, 256, 0, stream>>>(offs, csrc, ceid, ceav,
                                                           We, att, xlb, xrb, proj, bias,
                                                           aexp, denom, out_xnew);

    alpha_kernel<<<(EN_TOT * H_HEADS + 255) / 256, 256, 0, stream>>>(ei, aexp, denom, out_alpha);
}

// Round 8
// 186.435 us; speedup vs baseline: 30.5187x; 1.0944x over previous
//
#include <hip/hip_runtime.h>
#include <math.h>

#define N_NODES 50000
#define N_EDGES 400000
#define EN_TOT  450000
#define IN_DIM  128
#define H_HEADS 8
#define C_CH    32
#define HC      256
#define NEG_SLOPE 0.2f

typedef __attribute__((ext_vector_type(8))) short bf16x8;
typedef __attribute__((ext_vector_type(4))) float f32x4;

// ---------------- workspace layout (float slots) ----------------
// UNIT DISCIPLINE: sizes in FLOAT slots; bf16 regions = count/2 slots.
#define OFF_XLB   0                                   // x_l bf16 [N,256] -> N*128 floats
#define OFF_XRB   (OFF_XLB + N_NODES * 128)           // x_r bf16 [N,256]
#define OFF_PROJ  (OFF_XRB + N_NODES * 128)           // proj fp32 [N,32]
#define OFF_AEXP  (OFF_PROJ + N_NODES * C_CH)         // aexp [E+N,8] fp32
#define OFF_WCAT  (OFF_AEXP + EN_TOT * H_HEADS)       // Wcat bf16 [544,128]: 69632 shorts = 34816 floats
#define OFF_PART  (OFF_WCAT + 34816)                  // partial sums [1024]
#define OFF_MEAN  (OFF_PART + 1024)                   // mean scalar [1]
#define OFF_PAD   (OFF_MEAN + 1)                      // pad to 16B boundary for int4
#define OFF_CSR4  (OFF_PAD + 3)                       // packed csr int4 [E+N] -> 4*(E+N) slots (16B-aligned)
#define OFF_DEG   (OFF_CSR4 + EN_TOT * 4)             // deg  [N]
#define OFF_OFFS  (OFF_DEG + N_NODES)                 // offs [N+1]
#define OFF_CUR   (OFF_OFFS + N_NODES + 1)            // cursor [N]
#define OFF_BSUM  (OFF_CUR + N_NODES)                 // block sums [256]

#define SCAN_B 196   // ceil(50000/256)

// ---------------- fp32 -> bf16 (RNE) ----------------
__device__ __forceinline__ unsigned f2bf(float f) {
    unsigned u = __float_as_uint(f);
    u += 0x7fffu + ((u >> 16) & 1u);
    return u >> 16;
}
__device__ __forceinline__ float bflo(unsigned u) { return __uint_as_float(u << 16); }
__device__ __forceinline__ float bfhi(unsigned u) { return __uint_as_float(u & 0xffff0000u); }

// ---------------- convert weights Wcat=[Wl;Wr;Wproj] [544,128] to bf16 ----------------
#define WCHUNKS 8704              // 544*128/8
__global__ __launch_bounds__(256) void convert_w_kernel(
    const float* __restrict__ Wl, const float* __restrict__ Wr, const float* __restrict__ Wproj,
    unsigned short* __restrict__ wcat)
{
    int c = blockIdx.x * 256 + threadIdx.x;
    if (c >= WCHUNKS) return;
    int j = (c * 8) >> 7, k = (c * 8) & 127;
    const float* src = (j < 256 ? Wl + (size_t)j * 128
                                : (j < 512 ? Wr + (size_t)(j - 256) * 128
                                           : Wproj + (size_t)(j - 512) * 128)) + k;
    float4 a = ((const float4*)src)[0];
    float4 b = ((const float4*)src)[1];
    uint4 o;
    o.x = f2bf(a.x) | (f2bf(a.y) << 16);
    o.y = f2bf(a.z) | (f2bf(a.w) << 16);
    o.z = f2bf(b.x) | (f2bf(b.y) << 16);
    o.w = f2bf(b.z) | (f2bf(b.w) << 16);
    ((uint4*)wcat)[c] = o;
}

// ---------------- fused hist (over dst) + edge_attr partial sums ----------------
__global__ __launch_bounds__(256) void hist_mean_kernel(
    const int* __restrict__ ei, const float* __restrict__ ea,
    int* __restrict__ deg, float* __restrict__ part)
{
    __shared__ float sd[256];
    int t = threadIdx.x;
    int g = blockIdx.x * 256 + t;
    float s = 0.f;
    for (int i = g; i < N_EDGES; i += 1024 * 256) s += ea[i];
    for (int i = g; i < EN_TOT; i += 1024 * 256) {
        int d = (i < N_EDGES) ? ei[N_EDGES + i] : (i - N_EDGES);
        atomicAdd(&deg[d], 1);
    }
    sd[t] = s; __syncthreads();
    for (int w = 128; w > 0; w >>= 1) { if (t < w) sd[t] += sd[t + w]; __syncthreads(); }
    if (t == 0) part[blockIdx.x] = sd[0];
}

__global__ void mean_final_kernel(const float* __restrict__ part, float* __restrict__ mean_out) {
    __shared__ float sd[256];
    int t = threadIdx.x;
    float s = part[t] + part[t + 256] + part[t + 512] + part[t + 768];
    sd[t] = s; __syncthreads();
    for (int w = 128; w > 0; w >>= 1) { if (t < w) sd[t] += sd[t + w]; __syncthreads(); }
    if (t == 0) mean_out[0] = sd[0] / (float)N_EDGES;
}

// ---------------- parallel 3-phase exclusive scan of deg[50000] ----------------
__global__ __launch_bounds__(256) void scan_part_kernel(const int* __restrict__ deg,
                                                        int* __restrict__ bsum) {
    __shared__ int sd[256];
    int t = threadIdx.x;
    int i = blockIdx.x * 256 + t;
    int v = (i < N_NODES) ? deg[i] : 0;
    sd[t] = v; __syncthreads();
    for (int w = 128; w > 0; w >>= 1) { if (t < w) sd[t] += sd[t + w]; __syncthreads(); }
    if (t == 0) bsum[blockIdx.x] = sd[0];
}

__global__ __launch_bounds__(256) void scan_mid_kernel(int* __restrict__ bsum) {
    __shared__ int sd[256];
    int t = threadIdx.x;
    int v = (t < SCAN_B) ? bsum[t] : 0;
    sd[t] = v; __syncthreads();
    #pragma unroll
    for (int ofs = 1; ofs < 256; ofs <<= 1) {
        int u = (t >= ofs) ? sd[t - ofs] : 0;
        __syncthreads();
        sd[t] += u;
        __syncthreads();
    }
    if (t < SCAN_B) bsum[t] = sd[t] - v;   // exclusive
}

__global__ __launch_bounds__(256) void scan_final_kernel(
    const int* __restrict__ deg, const int* __restrict__ bsum,
    int* __restrict__ offs, int* __restrict__ cur) {
    __shared__ int sd[256];
    int t = threadIdx.x;
    int i = blockIdx.x * 256 + t;
    int v = (i < N_NODES) ? deg[i] : 0;
    sd[t] = v; __syncthreads();
    #pragma unroll
    for (int ofs = 1; ofs < 256; ofs <<= 1) {
        int u = (t >= ofs) ? sd[t - ofs] : 0;
        __syncthreads();
        sd[t] += u;
        __syncthreads();
    }
    int excl = bsum[blockIdx.x] + sd[t] - v;
    if (i < N_NODES) { offs[i] = excl; cur[i] = excl; }
    if (i == N_NODES - 1) offs[N_NODES] = excl + v;
}

// ---------------- scatter into packed CSR: int4 {src, eid, eav_bits, 0} ----------------
__global__ __launch_bounds__(256) void scatter_kernel(
    const int* __restrict__ ei, const float* __restrict__ edge_attr,
    const float* __restrict__ mean_attr, int* __restrict__ cur,
    int4* __restrict__ csr4)
{
    int e = blockIdx.x * 256 + threadIdx.x;
    if (e >= EN_TOT) return;
    int s, d; float eav;
    if (e < N_EDGES) { s = ei[e]; d = ei[N_EDGES + e]; eav = edge_attr[e]; }
    else { s = e - N_EDGES; d = s; eav = mean_attr[0]; }
    int pos = atomicAdd(&cur[d], 1);
    csr4[pos] = make_int4(s, e, __float_as_int(eav), 0);
}

// ---------------- MFMA GEMM: fp32 x converted inline, bf16 out xl/xr, fp32 proj ----------------
#define GM 128
#define GN 64

__global__ __launch_bounds__(256) void gemm_mfma_kernel(
    const float* __restrict__ x, const unsigned short* __restrict__ wcat,
    unsigned short* __restrict__ xlb, unsigned short* __restrict__ xrb,
    float* __restrict__ proj)
{
    __shared__ unsigned short As[GM * 128];   // 32 KB
    __shared__ unsigned short Bs[GN * 128];   // 16 KB
    const int t = threadIdx.x;
    const int m0 = blockIdx.x * GM;
    const int n0 = blockIdx.y * GN;

    // stage A: read x fp32, convert to bf16 in-reg, swizzled LDS write
    #pragma unroll
    for (int cc = 0; cc < 8; ++cc) {
        int c = t + cc * 256;
        int r = c >> 4;
        int k0 = (c & 15) * 8;
        int row = m0 + r;
        uint4 o = make_uint4(0, 0, 0, 0);
        if (row < N_NODES) {
            const float* p = x + (size_t)row * IN_DIM + k0;
            float4 a = ((const float4*)p)[0];
            float4 b = ((const float4*)p)[1];
            o.x = f2bf(a.x) | (f2bf(a.y) << 16);
            o.y = f2bf(a.z) | (f2bf(a.w) << 16);
            o.z = f2bf(b.x) | (f2bf(b.y) << 16);
            o.w = f2bf(b.z) | (f2bf(b.w) << 16);
        }
        int byte = (r * 256 + k0 * 2) ^ ((r & 7) << 4);
        *((uint4*)((char*)As + byte)) = o;
    }
    #pragma unroll
    for (int cc = 0; cc < 4; ++cc) {
        int c = t + cc * 256;
        int r = c >> 4;
        int k0 = (c & 15) * 8;
        int j = n0 + r;
        uint4 v = make_uint4(0, 0, 0, 0);
        if (j < 544) v = *((const uint4*)(wcat + (size_t)j * 128 + k0));
        int byte = (r * 256 + k0 * 2) ^ ((r & 7) << 4);
        *((uint4*)((char*)Bs + byte)) = v;
    }
    __syncthreads();

    const int wid = t >> 6, lane = t & 63;
    const int wr = wid >> 1, wc = wid & 1;
    const int lrow = lane & 15;
    const int kgrp = (lane >> 4) * 8;

    f32x4 acc[4][2] = {};
    #pragma unroll
    for (int kk = 0; kk < 4; ++kk) {
        bf16x8 a[4], b[2];
        #pragma unroll
        for (int fm = 0; fm < 4; ++fm) {
            int r = wr * 64 + fm * 16 + lrow;
            int byte = (r * 256 + (kk * 32 + kgrp) * 2) ^ ((r & 7) << 4);
            a[fm] = *((const bf16x8*)((const char*)As + byte));
        }
        #pragma unroll
        for (int fn = 0; fn < 2; ++fn) {
            int r = wc * 32 + fn * 16 + lrow;
            int byte = (r * 256 + (kk * 32 + kgrp) * 2) ^ ((r & 7) << 4);
            b[fn] = *((const bf16x8*)((const char*)Bs + byte));
        }
        #pragma unroll
        for (int fm = 0; fm < 4; ++fm)
            #pragma unroll
            for (int fn = 0; fn < 2; ++fn)
                acc[fm][fn] = __builtin_amdgcn_mfma_f32_16x16x32_bf16(a[fm], b[fn], acc[fm][fn], 0, 0, 0);
    }

    // C layout: row = (lane>>4)*4 + reg, col = lane&15  (m89-verified)
    const int crow0 = (lane >> 4) * 4;
    const int ccol = lane & 15;
    #pragma unroll
    for (int fm = 0; fm < 4; ++fm) {
        #pragma unroll
        for (int fn = 0; fn < 2; ++fn) {
            #pragma unroll
            for (int r = 0; r < 4; ++r) {
                int row = m0 + wr * 64 + fm * 16 + crow0 + r;
                int col = n0 + wc * 32 + fn * 16 + ccol;
                if (row >= N_NODES) continue;
                float v = acc[fm][fn][r];
                if (col < 256)      xlb[(size_t)row * HC + col] = (unsigned short)f2bf(v);
                else if (col < 512) xrb[(size_t)row * HC + (col - 256)] = (unsigned short)f2bf(v);
                else if (col < 544) proj[(size_t)row * C_CH + (col - 512)] = v;
            }
        }
    }
}

// ---------------- fused node aggregation v2 ----------------
// One wave per node; 32 lanes per edge (8 ch/lane, uint4 gathers), 2 edges/wave-step,
// 1-pair-deep pipeline. Fused alpha tail (re-reads just-written aexp through L2).
__global__ __launch_bounds__(256) void node_agg_kernel(
    const int* __restrict__ offs, const int4* __restrict__ csr4,
    const float* __restrict__ We, const float* __restrict__ att,
    const unsigned short* __restrict__ xlb, const unsigned short* __restrict__ xrb,
    const float* __restrict__ proj, const float* __restrict__ bias,
    float* __restrict__ aexp_out, float* __restrict__ alpha_out, float* __restrict__ xnew)
{
    const int l = threadIdx.x & 63;
    const int d = blockIdx.x * 4 + (threadIdx.x >> 6);
    if (d >= N_NODES) return;
    const int half = l >> 5;     // which edge of the pair this lane works on
    const int sl = l & 31;       // channel block: ch sl*8 .. sl*8+7 (head sl>>2)

    const float4 we0 = ((const float4*)We)[sl * 2];
    const float4 we1 = ((const float4*)We)[sl * 2 + 1];
    const float4 at0 = ((const float4*)att)[sl * 2];
    const float4 at1 = ((const float4*)att)[sl * 2 + 1];
    const float wev[8] = {we0.x, we0.y, we0.z, we0.w, we1.x, we1.y, we1.z, we1.w};
    const float atv[8] = {at0.x, at0.y, at0.z, at0.w, at1.x, at1.y, at1.z, at1.w};

    const uint4 vru = ((const uint4*)(xrb + (size_t)d * HC))[sl];
    float vr[8];
    vr[0] = bflo(vru.x); vr[1] = bfhi(vru.x); vr[2] = bflo(vru.y); vr[3] = bfhi(vru.y);
    vr[4] = bflo(vru.z); vr[5] = bfhi(vru.z); vr[6] = bflo(vru.w); vr[7] = bfhi(vru.w);

    const int beg = offs[d];
    const int end = offs[d + 1];

    float acc[8] = {0.f, 0.f, 0.f, 0.f, 0.f, 0.f, 0.f, 0.f};
    float den = 0.f;

    int i = beg;
    int4 c0 = make_int4(0, 0, 0, 0);
    uint4 vl0 = make_uint4(0, 0, 0, 0);
    if (i + half < end) {
        c0 = csr4[i + half];
        vl0 = ((const uint4*)(xlb + (size_t)c0.x * HC))[sl];
    }
    while (i < end) {
        const int ni = i + 2;
        int4 c1 = make_int4(0, 0, 0, 0);
        uint4 vl1 = make_uint4(0, 0, 0, 0);
        if (ni + half < end) {
            c1 = csr4[ni + half];
            vl1 = ((const uint4*)(xlb + (size_t)c1.x * HC))[sl];
        }

        const float ea = __int_as_float(c0.z);
        float xv[8];
        xv[0] = bflo(vl0.x); xv[1] = bfhi(vl0.x); xv[2] = bflo(vl0.y); xv[3] = bfhi(vl0.y);
        xv[4] = bflo(vl0.z); xv[5] = bfhi(vl0.z); xv[6] = bflo(vl0.w); xv[7] = bfhi(vl0.w);

        float tt = 0.f;
        #pragma unroll
        for (int j = 0; j < 8; ++j) {
            float m = xv[j] + vr[j] + ea * wev[j];
            m = fmaxf(m, NEG_SLOPE * m);      // leaky_relu (slope<1)
            tt += m * atv[j];
        }
        // reduce over the 4 lanes of this head (8 ch in-register already)
        tt += __shfl_xor(tt, 1);
        tt += __shfl_xor(tt, 2);
        float aex = __expf(tt);               // no max-subtraction: logits O(1)
        const bool valid = (i + half) < end;
        aex = valid ? aex : 0.f;
        if (valid && (sl & 3) == 0)
            aexp_out[(size_t)c0.y * H_HEADS + (sl >> 2)] = aex;
        #pragma unroll
        for (int j = 0; j < 8; ++j) acc[j] += aex * xv[j];
        den += aex;

        c0 = c1; vl0 = vl1; i = ni;
    }

    // merge the two edge-halves (same channels, same head)
    den += __shfl_xor(den, 32);
    #pragma unroll
    for (int j = 0; j < 8; ++j) acc[j] += __shfl_xor(acc[j], 32);

    // ---- fused alpha: all lanes have node den for head sl>>2; lane h*4 holds head h
    const float den_h = __shfl(den, ((l & 7) << 2));
    const float rden = 1.f / den_h;
    for (int b = beg; b < end; b += 8) {
        const int idx = b + (l >> 3);
        if (idx < end) {
            const int e = csr4[idx].y;
            const float ax = aexp_out[(size_t)e * H_HEADS + (l & 7)];
            alpha_out[(size_t)e * H_HEADS + (l & 7)] = ax * rden;
        }
    }

    // ---- normalize per head, mean over heads, epilogue
    const float inv = 1.f / den;
    #pragma unroll
    for (int j = 0; j < 8; ++j) acc[j] *= inv;
    #pragma unroll
    for (int mask = 4; mask <= 16; mask <<= 1)
        #pragma unroll
        for (int j = 0; j < 8; ++j) acc[j] += __shfl_xor(acc[j], mask);
    // lane sl (<4, half 0) now holds head-summed channels sl*8 .. sl*8+7
    if (half == 0 && sl < 4) {
        const float4 bi0 = ((const float4*)bias)[sl * 2];
        const float4 bi1 = ((const float4*)bias)[sl * 2 + 1];
        const float4 pr0 = ((const float4*)(proj + (size_t)d * C_CH))[sl * 2];
        const float4 pr1 = ((const float4*)(proj + (size_t)d * C_CH))[sl * 2 + 1];
        float4 r0, r1;
        r0.x = fmaxf(acc[0] * 0.125f + bi0.x, 0.f) + pr0.x;
        r0.y = fmaxf(acc[1] * 0.125f + bi0.y, 0.f) + pr0.y;
        r0.z = fmaxf(acc[2] * 0.125f + bi0.z, 0.f) + pr0.z;
        r0.w = fmaxf(acc[3] * 0.125f + bi0.w, 0.f) + pr0.w;
        r1.x = fmaxf(acc[4] * 0.125f + bi1.x, 0.f) + pr1.x;
        r1.y = fmaxf(acc[5] * 0.125f + bi1.y, 0.f) + pr1.y;
        r1.z = fmaxf(acc[6] * 0.125f + bi1.z, 0.f) + pr1.z;
        r1.w = fmaxf(acc[7] * 0.125f + bi1.w, 0.f) + pr1.w;
        ((float4*)(xnew + (size_t)d * C_CH))[sl * 2] = r0;
        ((float4*)(xnew + (size_t)d * C_CH))[sl * 2 + 1] = r1;
    }
}

extern "C" void kernel_launch(void* const* d_in, const int* in_sizes, int n_in,
                              void* d_out, int out_size, void* d_ws, size_t ws_size,
                              hipStream_t stream) {
    const float* x         = (const float*)d_in[0];
    const int*   ei        = (const int*)d_in[1];
    const float* edge_attr = (const float*)d_in[2];
    // d_in[3] = batch (unused)
    const float* Wl        = (const float*)d_in[4];
    const float* Wr        = (const float*)d_in[5];
    const float* We        = (const float*)d_in[6];
    const float* att       = (const float*)d_in[7];
    const float* bias      = (const float*)d_in[8];
    const float* Wproj     = (const float*)d_in[9];

    float* ws    = (float*)d_ws;
    unsigned short* xlb  = (unsigned short*)(ws + OFF_XLB);
    unsigned short* xrb  = (unsigned short*)(ws + OFF_XRB);
    float* proj  = ws + OFF_PROJ;
    float* aexp  = ws + OFF_AEXP;
    unsigned short* wcat = (unsigned short*)(ws + OFF_WCAT);
    float* part  = ws + OFF_PART;
    float* meanp = ws + OFF_MEAN;
    int4*  csr4  = (int4*)(ws + OFF_CSR4);
    int*   deg   = (int*)(ws + OFF_DEG);
    int*   offs  = (int*)(ws + OFF_OFFS);
    int*   cur   = (int*)(ws + OFF_CUR);
    int*   bsum  = (int*)(ws + OFF_BSUM);

    float* out_xnew  = (float*)d_out;
    float* out_alpha = (float*)d_out + (size_t)N_NODES * C_CH;

    hipMemsetAsync(deg, 0, N_NODES * sizeof(int), stream);

    convert_w_kernel<<<(WCHUNKS + 255) / 256, 256, 0, stream>>>(Wl, Wr, Wproj, wcat);

    hist_mean_kernel<<<1024, 256, 0, stream>>>(ei, edge_attr, deg, part);
    mean_final_kernel<<<1, 256, 0, stream>>>(part, meanp);

    scan_part_kernel<<<SCAN_B, 256, 0, stream>>>(deg, bsum);
    scan_mid_kernel<<<1, 256, 0, stream>>>(bsum);
    scan_final_kernel<<<SCAN_B, 256, 0, stream>>>(deg, bsum, offs, cur);

    scatter_kernel<<<(EN_TOT + 255) / 256, 256, 0, stream>>>(ei, edge_attr, meanp, cur, csr4);

    dim3 ggrid((N_NODES + GM - 1) / GM, (544 + GN - 1) / GN);
    gemm_mfma_kernel<<<ggrid, 256, 0, stream>>>(x, wcat, xlb, xrb, proj);

    node_agg_kernel<<<(N_NODES + 3) / 4, 256, 0, stream>>>(offs, csr4, We, att, xlb, xrb,
                                                           proj, bias, aexp, out_alpha, out_xnew);
}